// Round 3
// baseline (575.751 us; speedup 1.0000x reference)
//
#include <hip/hip_runtime.h>
#include <hip/hip_bf16.h>
#include <cstdint>
#include <cstddef>

// ---------- types ----------
typedef short bf16x8 __attribute__((ext_vector_type(8)));   // 8 bf16 (4 VGPRs) MFMA A/B frag
typedef float floatx4 __attribute__((ext_vector_type(4)));  // MFMA C/D frag
typedef unsigned short u16;

// Problem constants
constexpr int B = 4, S = 2048, D = 512, H = 8, DH = 64;
constexpr int M_ROWS = B * S;          // 8192
constexpr int D4 = 4 * D;              // 2048
// Q pre-scale: 1/sqrt(DH) * log2(e) so attention uses exp2 directly
constexpr float QSCALE = 0.18033688011112042f;

__device__ __forceinline__ u16 f2b(float f) {
  unsigned u = __builtin_bit_cast(unsigned, f);
  u += 0x7fff + ((u >> 16) & 1);       // RNE
  return (u16)(u >> 16);
}

__device__ __forceinline__ bf16x8 ldfrag(const u16* p) {
  return *reinterpret_cast<const bf16x8*>(p);
}

__device__ __forceinline__ floatx4 mfma16(bf16x8 a, bf16x8 b, floatx4 c) {
  return __builtin_amdgcn_mfma_f32_16x16x32_bf16(a, b, c, 0, 0, 0);
}

__device__ __forceinline__ ushort4 f2b4(float4 v) {
  ushort4 r;
  r.x = f2b(v.x); r.y = f2b(v.y); r.z = f2b(v.z); r.w = f2b(v.w);
  return r;
}

// ---------- cast fp32 -> bf16, 4 elems/thread ----------
__global__ void cast4_kernel(const float4* __restrict__ in, ushort4* __restrict__ out, int n4) {
  int i = blockIdx.x * blockDim.x + threadIdx.x;
  if (i < n4) out[i] = f2b4(in[i]);
}

// ---------- fused weight casts (W1, W2, Wq, Wk, Wv, Wo) ----------
__global__ void cast_w_kernel(const float4* __restrict__ w1, const float4* __restrict__ w2,
                              const float4* __restrict__ wq, const float4* __restrict__ wk,
                              const float4* __restrict__ wv, const float4* __restrict__ wo,
                              ushort4* __restrict__ w1b, ushort4* __restrict__ w2b,
                              ushort4* __restrict__ wqb, ushort4* __restrict__ wkb,
                              ushort4* __restrict__ wvb, ushort4* __restrict__ wob) {
  int i = blockIdx.x * blockDim.x + threadIdx.x;
  constexpr int N1 = (D4 * D) / 4;     // 262144
  constexpr int NS = (D * D) / 4;      // 65536
  if (i < N1) { w1b[i] = f2b4(w1[i]); return; }
  i -= N1;
  if (i < N1) { w2b[i] = f2b4(w2[i]); return; }
  i -= N1;
  const int sel = i >> 16, off = i & (NS - 1);
  const float4* src = sel == 0 ? wq : sel == 1 ? wk : sel == 2 ? wv : wo;
  ushort4* dst = sel == 0 ? wqb : sel == 1 ? wkb : sel == 2 ? wvb : wob;
  dst[off] = f2b4(src[off]);
}

// ---------- fused QKV GEMM (K=512 compile-time, reg double-buffer prefetch) ----------
// block 256 = 4 waves; block tile 128x128; wave tile 64x64
// z: 0->q [B,H,S,DH] (pre-scaled by QSCALE), 1->k [B,H,S,DH], 2->vT [B,H,DH,S]
__global__ __launch_bounds__(256) void qkv_gemm(
    const u16* __restrict__ xb,
    const u16* __restrict__ wq, const u16* __restrict__ wk, const u16* __restrict__ wv,
    u16* __restrict__ q, u16* __restrict__ k, u16* __restrict__ vT) {
  const int which = blockIdx.z;
  const u16* __restrict__ W = which == 0 ? wq : (which == 1 ? wk : wv);
  const int wave = threadIdx.x >> 6, lane = threadIdx.x & 63;
  const int quad = lane >> 4, l16 = lane & 15;
  const int row0 = blockIdx.y * 128 + (wave >> 1) * 64;
  const int col0 = blockIdx.x * 128 + (wave & 1) * 64;

  floatx4 acc[4][4];
#pragma unroll
  for (int i = 0; i < 4; i++)
#pragma unroll
    for (int j = 0; j < 4; j++) acc[i][j] = (floatx4){0.f,0.f,0.f,0.f};

  const u16* Ap = xb + (size_t)(row0 + l16) * D + quad * 8;
  const u16* Bp = W  + (size_t)(col0 + l16) * D + quad * 8;

  bf16x8 a[2][4], b[2][4];
#pragma unroll
  for (int i = 0; i < 4; i++) a[0][i] = ldfrag(Ap + (size_t)i * 16 * D);
#pragma unroll
  for (int j = 0; j < 4; j++) b[0][j] = ldfrag(Bp + (size_t)j * 16 * D);

#pragma unroll 16
  for (int kc = 0; kc < D; kc += 32) {
    const int cur = (kc >> 5) & 1;
    if (kc + 32 < D) {
#pragma unroll
      for (int i = 0; i < 4; i++) a[cur ^ 1][i] = ldfrag(Ap + (size_t)i * 16 * D + kc + 32);
#pragma unroll
      for (int j = 0; j < 4; j++) b[cur ^ 1][j] = ldfrag(Bp + (size_t)j * 16 * D + kc + 32);
    }
#pragma unroll
    for (int i = 0; i < 4; i++)
#pragma unroll
      for (int j = 0; j < 4; j++) acc[i][j] = mfma16(a[cur][i], b[cur][j], acc[i][j]);
  }

  const float oscale = (which == 0) ? QSCALE : 1.0f;
  u16* dst01 = which == 0 ? q : k;
#pragma unroll
  for (int i = 0; i < 4; i++) {
#pragma unroll
    for (int j = 0; j < 4; j++) {
      const int gn = col0 + j * 16 + l16;       // output feature = h*64+dh
      const int h = gn >> 6, dh = gn & 63;
#pragma unroll
      for (int r = 0; r < 4; r++) {
        const int gm = row0 + i * 16 + quad * 4 + r;   // b*S + s
        const int bb = gm >> 11, s = gm & 2047;
        const u16 val = f2b(acc[i][j][r] * oscale);
        if (which < 2) {
          dst01[((((size_t)bb * H + h) * S) + s) * DH + dh] = val;
        } else {
          vT[((((size_t)bb * H + h) * DH) + dh) * S + s] = val;
        }
      }
    }
  }
}

// ---------- generic GEMM  y = A @ W.T  (A:[M,K] bf16, W:[N,K] bf16) ----------
// Compile-time K; NI = wave-tile N in 16-col subtiles (4 -> 64, 2 -> 32).
// Block = 4 waves arranged 2(M) x 2(N): block tile 128 x (NI*32).
// EPI 0: store fp32; EPI 1: +bias, relu, store bf16; EPI 2: +bias, store fp32
template <int EPI, int K, int NI>
__global__ __launch_bounds__(256) void gemm_bt(
    const u16* __restrict__ A, const u16* __restrict__ W,
    const float* __restrict__ bias, void* __restrict__ out,
    int M, int N) {
  const int wave = threadIdx.x >> 6, lane = threadIdx.x & 63;
  const int quad = lane >> 4, l16 = lane & 15;
  const int row0 = blockIdx.y * 128 + (wave >> 1) * 64;
  const int col0 = blockIdx.x * (NI * 32) + (wave & 1) * (NI * 16);

  floatx4 acc[4][NI];
#pragma unroll
  for (int i = 0; i < 4; i++)
#pragma unroll
    for (int j = 0; j < NI; j++) acc[i][j] = (floatx4){0.f,0.f,0.f,0.f};

  const u16* Ap = A + (size_t)(row0 + l16) * K + quad * 8;
  const u16* Bp = W + (size_t)(col0 + l16) * K + quad * 8;

  bf16x8 a[2][4], b[2][NI];
#pragma unroll
  for (int i = 0; i < 4; i++) a[0][i] = ldfrag(Ap + (size_t)i * 16 * K);
#pragma unroll
  for (int j = 0; j < NI; j++) b[0][j] = ldfrag(Bp + (size_t)j * 16 * K);

#pragma unroll 16
  for (int kc = 0; kc < K; kc += 32) {
    const int cur = (kc >> 5) & 1;
    if (kc + 32 < K) {
#pragma unroll
      for (int i = 0; i < 4; i++) a[cur ^ 1][i] = ldfrag(Ap + (size_t)i * 16 * K + kc + 32);
#pragma unroll
      for (int j = 0; j < NI; j++) b[cur ^ 1][j] = ldfrag(Bp + (size_t)j * 16 * K + kc + 32);
    }
#pragma unroll
    for (int i = 0; i < 4; i++)
#pragma unroll
      for (int j = 0; j < NI; j++) acc[i][j] = mfma16(a[cur][i], b[cur][j], acc[i][j]);
  }

#pragma unroll
  for (int i = 0; i < 4; i++) {
#pragma unroll
    for (int j = 0; j < NI; j++) {
      const int gn = col0 + j * 16 + l16;
      const float bv = (EPI == 1 || EPI == 2) ? bias[gn] : 0.f;
#pragma unroll
      for (int r = 0; r < 4; r++) {
        const int gm = row0 + i * 16 + quad * 4 + r;
        float v = acc[i][j][r] + bv;
        if (EPI == 0) {
          ((float*)out)[(size_t)gm * N + gn] = v;
        } else if (EPI == 1) {
          v = v > 0.f ? v : 0.f;
          ((u16*)out)[(size_t)gm * N + gn] = f2b(v);
        } else {
          ((float*)out)[(size_t)gm * N + gn] = v;
        }
      }
    }
  }
}

// ---------- fused flash attention, no-max softmax, reg-prefetched K/V ----------
// one wave per (b,h, 16-query tile); block = 4 waves; K-tile = 64
// K and V fragments for tile t+1 are loaded into a second register buffer at
// the top of tile t's compute -> load latency (L2/L3, ~300-900 cyc) overlaps
// one full iteration; compiler emits fine-grained vmcnt (never 0).
constexpr int PSTRIDE = 72;  // u16 units; 144 B rows, 16B-aligned for ds_read_b128

__global__ __launch_bounds__(256) void attn_kernel(
    const u16* __restrict__ q, const u16* __restrict__ k,
    const u16* __restrict__ vT, u16* __restrict__ ctxb) {
  __shared__ __align__(16) u16 plds[4][16 * PSTRIDE];
  const int wave = threadIdx.x >> 6, lane = threadIdx.x & 63;
  const int quad = lane >> 4, l16 = lane & 15;
  // XCD swizzle: contiguous q-tile runs per XCD for K/V L2 locality
  const int blk = (blockIdx.x & 7) * (1024 / 8) + (blockIdx.x >> 3);
  const int w = blk * 4 + wave;
  const int bh = w >> 7;            // 128 q-tiles per (b,h)
  const int qt = w & 127;
  const int bb = bh >> 3, h = bh & 7;

  const u16* qp = q + ((size_t)bh * S + qt * 16 + l16) * DH + quad * 8;
  const bf16x8 qf0 = ldfrag(qp);
  const bf16x8 qf1 = ldfrag(qp + 32);
  const u16* kbase = k + (size_t)bh * S * DH + (size_t)l16 * DH + quad * 8;
  const u16* vbase = vT + (size_t)bh * DH * S + (size_t)l16 * S + quad * 8;

  floatx4 o[4];
#pragma unroll
  for (int c = 0; c < 4; c++) o[c] = (floatx4){0.f,0.f,0.f,0.f};
  float lacc[4] = {0.f, 0.f, 0.f, 0.f};

  u16* myp = plds[wave];
  u16* wp = myp + (quad * 4) * PSTRIDE + l16;        // write base
  const u16* rp = myp + l16 * PSTRIDE + quad * 8;    // read base (A-frag layout)

  bf16x8 kf[2][8], vf[2][8];
#pragma unroll
  for (int i = 0; i < 4; i++) {
    kf[0][2 * i]     = ldfrag(kbase + (size_t)i * 16 * DH);
    kf[0][2 * i + 1] = ldfrag(kbase + (size_t)i * 16 * DH + 32);
    vf[0][2 * i]     = ldfrag(vbase + (size_t)i * 16 * S);
    vf[0][2 * i + 1] = ldfrag(vbase + (size_t)i * 16 * S + 32);
  }

#pragma unroll 2
  for (int kt = 0; kt < S; kt += 64) {
    const int cur = (kt >> 6) & 1;
    if (kt + 64 < S) {
      const u16* kp = kbase + (size_t)(kt + 64) * DH;
      const u16* vp = vbase + kt + 64;
#pragma unroll
      for (int i = 0; i < 4; i++) {
        kf[cur ^ 1][2 * i]     = ldfrag(kp + (size_t)i * 16 * DH);
        kf[cur ^ 1][2 * i + 1] = ldfrag(kp + (size_t)i * 16 * DH + 32);
        vf[cur ^ 1][2 * i]     = ldfrag(vp + (size_t)i * 16 * S);
        vf[cur ^ 1][2 * i + 1] = ldfrag(vp + (size_t)i * 16 * S + 32);
      }
    }

    floatx4 sc[4];
#pragma unroll
    for (int i = 0; i < 4; i++) {
      floatx4 z = (floatx4){0.f,0.f,0.f,0.f};
      z = mfma16(qf0, kf[cur][2 * i], z);
      z = mfma16(qf1, kf[cur][2 * i + 1], z);
      sc[i] = z;
    }
#pragma unroll
    for (int r = 0; r < 4; r++) {
      float acc = 0.f;
#pragma unroll
      for (int i = 0; i < 4; i++) {
        const float p = __builtin_amdgcn_exp2f(sc[i][r]);
        acc += p;
        wp[r * PSTRIDE + i * 16] = f2b(p);
      }
      lacc[r] += acc;
    }
    asm volatile("s_waitcnt lgkmcnt(0)" ::: "memory");
    const bf16x8 pf0 = *reinterpret_cast<const bf16x8*>(rp);
    const bf16x8 pf1 = *reinterpret_cast<const bf16x8*>(rp + 32);
#pragma unroll
    for (int c = 0; c < 4; c++) {
      o[c] = mfma16(pf0, vf[cur][2 * c], o[c]);
      o[c] = mfma16(pf1, vf[cur][2 * c + 1], o[c]);
    }
  }

  // one-time l reduction across the 16 lanes sharing each row
  float inv[4];
#pragma unroll
  for (int r = 0; r < 4; r++) {
    float l = lacc[r];
#pragma unroll
    for (int d = 1; d < 16; d <<= 1) l += __shfl_xor(l, d);
    inv[r] = 1.0f / l;
  }

  const size_t crow_base = ((size_t)bb * S) * D + h * DH;
#pragma unroll
  for (int c = 0; c < 4; c++) {
    const int dh = c * 16 + l16;
#pragma unroll
    for (int r = 0; r < 4; r++) {
      const int s = qt * 16 + quad * 4 + r;
      ctxb[crow_base + (size_t)s * D + dh] = f2b(o[c][r] * inv[r]);
    }
  }
}

// ---------- layernorm: out = LN(resid + y) ----------
template <bool BF16OUT>
__global__ __launch_bounds__(256) void ln_kernel(
    const float* __restrict__ resid, const float* __restrict__ y,
    const float* __restrict__ g, const float* __restrict__ bvec,
    float* __restrict__ outF, u16* __restrict__ outB) {
  const int wave = threadIdx.x >> 6, lane = threadIdx.x & 63;
  const int row = blockIdx.x * 4 + wave;
  const float* rp = resid + (size_t)row * D + lane * 8;
  const float* yp = y + (size_t)row * D + lane * 8;
  float v[8];
  const float4 a0 = *(const float4*)rp, a1 = *(const float4*)(rp + 4);
  const float4 b0 = *(const float4*)yp, b1 = *(const float4*)(yp + 4);
  v[0] = a0.x + b0.x; v[1] = a0.y + b0.y; v[2] = a0.z + b0.z; v[3] = a0.w + b0.w;
  v[4] = a1.x + b1.x; v[5] = a1.y + b1.y; v[6] = a1.z + b1.z; v[7] = a1.w + b1.w;
  float sum = 0.f;
#pragma unroll
  for (int i = 0; i < 8; i++) sum += v[i];
#pragma unroll
  for (int d = 1; d < 64; d <<= 1) sum += __shfl_xor(sum, d);
  const float mu = sum * (1.f / D);
  float vs = 0.f;
#pragma unroll
  for (int i = 0; i < 8; i++) { const float t = v[i] - mu; vs += t * t; }
#pragma unroll
  for (int d = 1; d < 64; d <<= 1) vs += __shfl_xor(vs, d);
  const float rstd = rsqrtf(vs * (1.f / D) + 1e-5f);
#pragma unroll
  for (int i = 0; i < 8; i++) {
    const int col = lane * 8 + i;
    const float o = (v[i] - mu) * rstd * g[col] + bvec[col];
    outF[(size_t)row * D + col] = o;
    if (BF16OUT) outB[(size_t)row * D + col] = f2b(o);
  }
}

// ---------- workspace layout (bytes) ----------
constexpr size_t OFF_XB  = 0;                       // 8 MB  xb [8192,512] bf16
constexpr size_t OFF_WQB = 8u << 20;                // 512 KB
constexpr size_t OFF_WKB = OFF_WQB + (512u << 10);
constexpr size_t OFF_WVB = OFF_WKB + (512u << 10);
constexpr size_t OFF_WOB = OFF_WVB + (512u << 10);
constexpr size_t OFF_W1B = 10u << 20;               // 2 MB
constexpr size_t OFF_W2B = 12u << 20;               // 2 MB
constexpr size_t OFF_Q   = 14u << 20;               // 8 MB
constexpr size_t OFF_K   = 22u << 20;               // 8 MB
constexpr size_t OFF_VT  = 30u << 20;               // 8 MB
constexpr size_t OFF_CTX = 38u << 20;               // 8 MB
constexpr size_t OFF_Y   = 46u << 20;               // 16 MB fp32 (shared y1/y2)
constexpr size_t OFF_H   = 62u << 20;               // 16 MB fp32
constexpr size_t OFF_HB  = 78u << 20;               // 8 MB bf16
constexpr size_t OFF_M1B = 86u << 20;               // 32 MB bf16 [8192,2048]
// total 118 MB

extern "C" void kernel_launch(void* const* d_in, const int* in_sizes, int n_in,
                              void* d_out, int out_size, void* d_ws, size_t ws_size,
                              hipStream_t stream) {
  const float* x  = (const float*)d_in[0];
  const float* Wq = (const float*)d_in[1];
  const float* Wk = (const float*)d_in[2];
  const float* Wv = (const float*)d_in[3];
  const float* Wo = (const float*)d_in[4];
  const float* W1 = (const float*)d_in[5];
  const float* b1 = (const float*)d_in[6];
  const float* W2 = (const float*)d_in[7];
  const float* b2 = (const float*)d_in[8];
  const float* g1 = (const float*)d_in[9];
  const float* bb1 = (const float*)d_in[10];
  const float* g2 = (const float*)d_in[11];
  const float* bb2 = (const float*)d_in[12];

  char* ws = (char*)d_ws;
  u16* xb  = (u16*)(ws + OFF_XB);
  u16* wqb = (u16*)(ws + OFF_WQB);
  u16* wkb = (u16*)(ws + OFF_WKB);
  u16* wvb = (u16*)(ws + OFF_WVB);
  u16* wob = (u16*)(ws + OFF_WOB);
  u16* w1b = (u16*)(ws + OFF_W1B);
  u16* w2b = (u16*)(ws + OFF_W2B);
  u16* qb  = (u16*)(ws + OFF_Q);
  u16* kb  = (u16*)(ws + OFF_K);
  u16* vtb = (u16*)(ws + OFF_VT);
  u16* ctxb = (u16*)(ws + OFF_CTX);
  float* y = (float*)(ws + OFF_Y);
  float* hf = (float*)(ws + OFF_H);
  u16* hb  = (u16*)(ws + OFF_HB);
  u16* m1b = (u16*)(ws + OFF_M1B);

  // 1. casts (x separate; 6 weights fused into one launch)
  cast4_kernel<<<(M_ROWS * D / 4 + 255) / 256, 256, 0, stream>>>(
      (const float4*)x, (ushort4*)xb, M_ROWS * D / 4);
  {
    const int n4 = (D4 * D) / 4 * 2 + (D * D) / 4 * 4;   // 786432
    cast_w_kernel<<<(n4 + 255) / 256, 256, 0, stream>>>(
        (const float4*)W1, (const float4*)W2, (const float4*)Wq, (const float4*)Wk,
        (const float4*)Wv, (const float4*)Wo,
        (ushort4*)w1b, (ushort4*)w2b, (ushort4*)wqb, (ushort4*)wkb,
        (ushort4*)wvb, (ushort4*)wob);
  }

  // 2. QKV projections (q pre-scaled by QSCALE)
  qkv_gemm<<<dim3(D / 128, M_ROWS / 128, 3), 256, 0, stream>>>(xb, wqb, wkb, wvb, qb, kb, vtb);

  // 3. attention
  attn_kernel<<<(B * H * (S / 16)) / 4, 256, 0, stream>>>(qb, kb, vtb, ctxb);

  // 4. out-proj: y = ctx @ Wo.T (fp32); NI=2 -> 512 blocks (2/CU)
  gemm_bt<0, 512, 2><<<dim3(D / 64, M_ROWS / 128), 256, 0, stream>>>(
      ctxb, wob, nullptr, y, M_ROWS, D);

  // 5. h = LN(x + y)  -> hf fp32, hb bf16
  ln_kernel<true><<<M_ROWS / 4, 256, 0, stream>>>(x, y, g1, bb1, hf, hb);

  // 6. m1 = relu(h @ W1.T + b1) -> bf16; NI=4 -> 1024 blocks (4/CU)
  gemm_bt<1, 512, 4><<<dim3(D4 / 128, M_ROWS / 128), 256, 0, stream>>>(
      hb, w1b, b1, m1b, M_ROWS, D4);

  // 7. y = m1 @ W2.T + b2 -> fp32; NI=2 -> 512 blocks (2/CU)
  gemm_bt<2, 2048, 2><<<dim3(D / 64, M_ROWS / 128), 256, 0, stream>>>(
      m1b, w2b, b2, y, M_ROWS, D);

  // 8. out = LN(h + y)
  ln_kernel<false><<<M_ROWS / 4, 256, 0, stream>>>(hf, y, g2, bb2, (float*)d_out, nullptr);
}

// Round 4
// 399.119 us; speedup vs baseline: 1.4426x; 1.4426x over previous
//
#include <hip/hip_runtime.h>
#include <hip/hip_bf16.h>
#include <cstdint>
#include <cstddef>

// ---------- types ----------
typedef short bf16x8 __attribute__((ext_vector_type(8)));   // 8 bf16 (4 VGPRs) MFMA A/B frag
typedef float floatx4 __attribute__((ext_vector_type(4)));  // MFMA C/D frag
typedef unsigned short u16;

// Problem constants
constexpr int B = 4, S = 2048, D = 512, H = 8, DH = 64;
constexpr int M_ROWS = B * S;          // 8192
constexpr int D4 = 4 * D;              // 2048
// Q pre-scale: 1/sqrt(DH) * log2(e) so attention uses exp2 directly
constexpr float QSCALE = 0.18033688011112042f;

__device__ __forceinline__ u16 f2b(float f) {
  unsigned u = __builtin_bit_cast(unsigned, f);
  u += 0x7fff + ((u >> 16) & 1);       // RNE
  return (u16)(u >> 16);
}

__device__ __forceinline__ bf16x8 ldfrag(const u16* p) {
  return *reinterpret_cast<const bf16x8*>(p);
}

__device__ __forceinline__ floatx4 mfma16(bf16x8 a, bf16x8 b, floatx4 c) {
  return __builtin_amdgcn_mfma_f32_16x16x32_bf16(a, b, c, 0, 0, 0);
}

__device__ __forceinline__ ushort4 f2b4(float4 v) {
  ushort4 r;
  r.x = f2b(v.x); r.y = f2b(v.y); r.z = f2b(v.z); r.w = f2b(v.w);
  return r;
}

// ---------- cast fp32 -> bf16, 4 elems/thread ----------
__global__ void cast4_kernel(const float4* __restrict__ in, ushort4* __restrict__ out, int n4) {
  int i = blockIdx.x * blockDim.x + threadIdx.x;
  if (i < n4) out[i] = f2b4(in[i]);
}

// ---------- fused weight casts (W1, W2, Wq, Wk, Wv, Wo) ----------
__global__ void cast_w_kernel(const float4* __restrict__ w1, const float4* __restrict__ w2,
                              const float4* __restrict__ wq, const float4* __restrict__ wk,
                              const float4* __restrict__ wv, const float4* __restrict__ wo,
                              ushort4* __restrict__ w1b, ushort4* __restrict__ w2b,
                              ushort4* __restrict__ wqb, ushort4* __restrict__ wkb,
                              ushort4* __restrict__ wvb, ushort4* __restrict__ wob) {
  int i = blockIdx.x * blockDim.x + threadIdx.x;
  constexpr int N1 = (D4 * D) / 4;     // 262144
  constexpr int NS = (D * D) / 4;      // 65536
  if (i < N1) { w1b[i] = f2b4(w1[i]); return; }
  i -= N1;
  if (i < N1) { w2b[i] = f2b4(w2[i]); return; }
  i -= N1;
  const int sel = i >> 16, off = i & (NS - 1);
  const float4* src = sel == 0 ? wq : sel == 1 ? wk : sel == 2 ? wv : wo;
  ushort4* dst = sel == 0 ? wqb : sel == 1 ? wkb : sel == 2 ? wvb : wob;
  dst[off] = f2b4(src[off]);
}

// ---------- fused QKV GEMM (R2 form — simple direct-load MFMA) ----------
// block 256 = 4 waves; block tile 128x128; wave tile 64x64
// z: 0->q [B,H,S,DH] (pre-scaled by QSCALE), 1->k [B,H,S,DH], 2->vT [B,H,DH,S]
__global__ __launch_bounds__(256) void qkv_gemm(
    const u16* __restrict__ xb,
    const u16* __restrict__ wq, const u16* __restrict__ wk, const u16* __restrict__ wv,
    u16* __restrict__ q, u16* __restrict__ k, u16* __restrict__ vT) {
  const int which = blockIdx.z;
  const u16* __restrict__ W = which == 0 ? wq : (which == 1 ? wk : wv);
  const int wave = threadIdx.x >> 6, lane = threadIdx.x & 63;
  const int quad = lane >> 4, l16 = lane & 15;
  const int row0 = blockIdx.y * 128 + (wave >> 1) * 64;
  const int col0 = blockIdx.x * 128 + (wave & 1) * 64;

  floatx4 acc[4][4];
  for (int i = 0; i < 4; i++) for (int j = 0; j < 4; j++) acc[i][j] = (floatx4){0.f,0.f,0.f,0.f};

  const u16* Ap = xb + (size_t)(row0 + l16) * D + quad * 8;
  const u16* Bp = W  + (size_t)(col0 + l16) * D + quad * 8;
  for (int kc = 0; kc < D; kc += 32) {
    bf16x8 a[4], b[4];
#pragma unroll
    for (int i = 0; i < 4; i++) a[i] = ldfrag(Ap + (size_t)i * 16 * D + kc);
#pragma unroll
    for (int j = 0; j < 4; j++) b[j] = ldfrag(Bp + (size_t)j * 16 * D + kc);
#pragma unroll
    for (int i = 0; i < 4; i++)
#pragma unroll
      for (int j = 0; j < 4; j++) acc[i][j] = mfma16(a[i], b[j], acc[i][j]);
  }

  const float oscale = (which == 0) ? QSCALE : 1.0f;
  u16* dst01 = which == 0 ? q : k;
#pragma unroll
  for (int i = 0; i < 4; i++) {
#pragma unroll
    for (int j = 0; j < 4; j++) {
      const int gn = col0 + j * 16 + l16;       // output feature = h*64+dh
      const int h = gn >> 6, dh = gn & 63;
#pragma unroll
      for (int r = 0; r < 4; r++) {
        const int gm = row0 + i * 16 + quad * 4 + r;   // b*S + s
        const int bb = gm >> 11, s = gm & 2047;
        const u16 val = f2b(acc[i][j][r] * oscale);
        if (which < 2) {
          dst01[((((size_t)bb * H + h) * S) + s) * DH + dh] = val;
        } else {
          vT[((((size_t)bb * H + h) * DH) + dh) * S + s] = val;
        }
      }
    }
  }
}

// ---------- generic GEMM  y = A @ W.T  (R2 form) ----------
// EPI 0: store fp32; EPI 1: +bias, relu, store bf16; EPI 2: +bias, store fp32
template <int EPI>
__global__ __launch_bounds__(256) void gemm_bt(
    const u16* __restrict__ A, const u16* __restrict__ W,
    const float* __restrict__ bias, void* __restrict__ out,
    int M, int N, int K) {
  const int wave = threadIdx.x >> 6, lane = threadIdx.x & 63;
  const int quad = lane >> 4, l16 = lane & 15;
  const int row0 = blockIdx.y * 128 + (wave >> 1) * 64;
  const int col0 = blockIdx.x * 128 + (wave & 1) * 64;

  floatx4 acc[4][4];
  for (int i = 0; i < 4; i++) for (int j = 0; j < 4; j++) acc[i][j] = (floatx4){0.f,0.f,0.f,0.f};

  const u16* Ap = A + (size_t)(row0 + l16) * K + quad * 8;
  const u16* Bp = W + (size_t)(col0 + l16) * K + quad * 8;
  for (int kc = 0; kc < K; kc += 32) {
    bf16x8 a[4], b[4];
#pragma unroll
    for (int i = 0; i < 4; i++) a[i] = ldfrag(Ap + (size_t)i * 16 * K + kc);
#pragma unroll
    for (int j = 0; j < 4; j++) b[j] = ldfrag(Bp + (size_t)j * 16 * K + kc);
#pragma unroll
    for (int i = 0; i < 4; i++)
#pragma unroll
      for (int j = 0; j < 4; j++) acc[i][j] = mfma16(a[i], b[j], acc[i][j]);
  }

#pragma unroll
  for (int i = 0; i < 4; i++) {
#pragma unroll
    for (int j = 0; j < 4; j++) {
      const int gn = col0 + j * 16 + l16;
      const float bv = (EPI == 1 || EPI == 2) ? bias[gn] : 0.f;
#pragma unroll
      for (int r = 0; r < 4; r++) {
        const int gm = row0 + i * 16 + quad * 4 + r;
        float v = acc[i][j][r] + bv;
        if (EPI == 0) {
          ((float*)out)[(size_t)gm * N + gn] = v;
        } else if (EPI == 1) {
          v = v > 0.f ? v : 0.f;
          ((u16*)out)[(size_t)gm * N + gn] = f2b(v);
        } else {
          ((float*)out)[(size_t)gm * N + gn] = v;
        }
      }
    }
  }
}

// ---------- fused flash attention: 64 queries per wave, no-max softmax ----------
// One wave handles a 64-query tile (4 MFMA A-frags) x all S keys, K-tile = 64.
// K/V fragment loads per tile are shared by 4x the MFMA work vs the 16-query
// version -> L2-side K/V traffic and request count drop 4x (the R2/R3 wall).
// Grid = 256 blocks x 4 waves = 1024 waves = 1/SIMD; latency hidden by ILP
// (32 QK MFMAs, 64 exps, 32 PV MFMAs per tile, all independent chains).
constexpr int PSTRIDE = 72;  // u16 units; 144 B rows, 16B-aligned for ds_read_b128

__global__ __launch_bounds__(256) void attn_kernel(
    const u16* __restrict__ q, const u16* __restrict__ k,
    const u16* __restrict__ vT, u16* __restrict__ ctxb) {
  __shared__ __align__(16) u16 plds[4][64 * PSTRIDE];   // 36.9 KB: per-wave 64x64 P tile
  const int wave = threadIdx.x >> 6, lane = threadIdx.x & 63;
  const int quad = lane >> 4, l16 = lane & 15;
  // XCD swizzle: 256 blocks; HW sends block b to XCD b%8. Map so each XCD's
  // blocks cover 4 consecutive bh groups -> 4 x 512KB K/V per XCD L2.
  const int blk = (blockIdx.x & 7) * 32 + (blockIdx.x >> 3);
  const int w = blk * 4 + wave;     // 1024 wave ids
  const int bh = w >> 5;            // 32 waves (64q each) per (b,h)
  const int qt = w & 31;            // 64-query tile index within bh
  const int bb = bh >> 3, h = bh & 7;

  // Q fragments: 4 subtiles of 16 rows
  const u16* qp = q + ((size_t)bh * S + qt * 64 + l16) * DH + quad * 8;
  bf16x8 qf[4][2];
#pragma unroll
  for (int t = 0; t < 4; t++) {
    qf[t][0] = ldfrag(qp + (size_t)t * 16 * DH);
    qf[t][1] = ldfrag(qp + (size_t)t * 16 * DH + 32);
  }
  const u16* kbase = k + (size_t)bh * S * DH + (size_t)l16 * DH + quad * 8;
  const u16* vbase = vT + (size_t)bh * DH * S + (size_t)l16 * S + quad * 8;

  floatx4 o[4][4];                  // [q-subtile][dh-col-subtile]
#pragma unroll
  for (int t = 0; t < 4; t++)
#pragma unroll
    for (int c = 0; c < 4; c++) o[t][c] = (floatx4){0.f,0.f,0.f,0.f};
  float lacc[4][4];                 // [q-subtile][r]
#pragma unroll
  for (int t = 0; t < 4; t++)
#pragma unroll
    for (int r = 0; r < 4; r++) lacc[t][r] = 0.f;

  u16* myp = plds[wave];
  u16* wp = myp + (quad * 4) * PSTRIDE + l16;        // + t*16*PSTRIDE + r*PSTRIDE + i*16
  const u16* rp = myp + l16 * PSTRIDE + quad * 8;    // + t*16*PSTRIDE (A-frag layout)

  for (int kt = 0; kt < S; kt += 64) {
    // K fragments for this 64-key tile (shared across 4 q-subtiles)
    const u16* kp = kbase + (size_t)kt * DH;
    bf16x8 kf[8];
#pragma unroll
    for (int i = 0; i < 4; i++) {
      kf[2 * i]     = ldfrag(kp + (size_t)i * 16 * DH);
      kf[2 * i + 1] = ldfrag(kp + (size_t)i * 16 * DH + 32);
    }
    // V fragments (issued early so they overlap the QK/exp work)
    const u16* vp = vbase + kt;
    bf16x8 vf[8];
#pragma unroll
    for (int c = 0; c < 4; c++) {
      vf[2 * c]     = ldfrag(vp + (size_t)c * 16 * S);
      vf[2 * c + 1] = ldfrag(vp + (size_t)c * 16 * S + 32);
    }

    // QK^T: 32 MFMAs
    floatx4 sc[4][4];
#pragma unroll
    for (int t = 0; t < 4; t++)
#pragma unroll
      for (int i = 0; i < 4; i++) {
        floatx4 z = (floatx4){0.f,0.f,0.f,0.f};
        z = mfma16(qf[t][0], kf[2 * i], z);
        z = mfma16(qf[t][1], kf[2 * i + 1], z);
        sc[t][i] = z;
      }

    // exp2 + P -> LDS (C-layout rows -> A-layout read below)
#pragma unroll
    for (int t = 0; t < 4; t++)
#pragma unroll
      for (int r = 0; r < 4; r++) {
        float acc = 0.f;
#pragma unroll
        for (int i = 0; i < 4; i++) {
          const float p = __builtin_amdgcn_exp2f(sc[t][i][r]);
          acc += p;
          wp[(t * 16 + r) * PSTRIDE + i * 16] = f2b(p);
        }
        lacc[t][r] += acc;
      }

    // P @ V: 32 MFMAs (compiler inserts lgkmcnt for the LDS write->read dep)
#pragma unroll
    for (int t = 0; t < 4; t++) {
      const bf16x8 pf0 = *reinterpret_cast<const bf16x8*>(rp + (size_t)t * 16 * PSTRIDE);
      const bf16x8 pf1 = *reinterpret_cast<const bf16x8*>(rp + (size_t)t * 16 * PSTRIDE + 32);
#pragma unroll
      for (int c = 0; c < 4; c++) {
        o[t][c] = mfma16(pf0, vf[2 * c], o[t][c]);
        o[t][c] = mfma16(pf1, vf[2 * c + 1], o[t][c]);
      }
    }
  }

  // one-time l reduction across the 16 lanes sharing each row
  float inv[4][4];
#pragma unroll
  for (int t = 0; t < 4; t++)
#pragma unroll
    for (int r = 0; r < 4; r++) {
      float l = lacc[t][r];
#pragma unroll
      for (int d = 1; d < 16; d <<= 1) l += __shfl_xor(l, d);
      inv[t][r] = 1.0f / l;
    }

  const size_t crow_base = ((size_t)bb * S) * D + h * DH;
#pragma unroll
  for (int t = 0; t < 4; t++)
#pragma unroll
    for (int c = 0; c < 4; c++) {
      const int dh = c * 16 + l16;
#pragma unroll
      for (int r = 0; r < 4; r++) {
        const int s = qt * 64 + t * 16 + quad * 4 + r;
        ctxb[crow_base + (size_t)s * D + dh] = f2b(o[t][c][r] * inv[t][r]);
      }
    }
}

// ---------- layernorm: out = LN(resid + y) ----------
template <bool BF16OUT>
__global__ __launch_bounds__(256) void ln_kernel(
    const float* __restrict__ resid, const float* __restrict__ y,
    const float* __restrict__ g, const float* __restrict__ bvec,
    float* __restrict__ outF, u16* __restrict__ outB) {
  const int wave = threadIdx.x >> 6, lane = threadIdx.x & 63;
  const int row = blockIdx.x * 4 + wave;
  const float* rp = resid + (size_t)row * D + lane * 8;
  const float* yp = y + (size_t)row * D + lane * 8;
  float v[8];
  const float4 a0 = *(const float4*)rp, a1 = *(const float4*)(rp + 4);
  const float4 b0 = *(const float4*)yp, b1 = *(const float4*)(yp + 4);
  v[0] = a0.x + b0.x; v[1] = a0.y + b0.y; v[2] = a0.z + b0.z; v[3] = a0.w + b0.w;
  v[4] = a1.x + b1.x; v[5] = a1.y + b1.y; v[6] = a1.z + b1.z; v[7] = a1.w + b1.w;
  float sum = 0.f;
#pragma unroll
  for (int i = 0; i < 8; i++) sum += v[i];
#pragma unroll
  for (int d = 1; d < 64; d <<= 1) sum += __shfl_xor(sum, d);
  const float mu = sum * (1.f / D);
  float vs = 0.f;
#pragma unroll
  for (int i = 0; i < 8; i++) { const float t = v[i] - mu; vs += t * t; }
#pragma unroll
  for (int d = 1; d < 64; d <<= 1) vs += __shfl_xor(vs, d);
  const float rstd = rsqrtf(vs * (1.f / D) + 1e-5f);
#pragma unroll
  for (int i = 0; i < 8; i++) {
    const int col = lane * 8 + i;
    const float o = (v[i] - mu) * rstd * g[col] + bvec[col];
    outF[(size_t)row * D + col] = o;
    if (BF16OUT) outB[(size_t)row * D + col] = f2b(o);
  }
}

// ---------- workspace layout (bytes) ----------
constexpr size_t OFF_XB  = 0;                       // 8 MB  xb [8192,512] bf16
constexpr size_t OFF_WQB = 8u << 20;                // 512 KB
constexpr size_t OFF_WKB = OFF_WQB + (512u << 10);
constexpr size_t OFF_WVB = OFF_WKB + (512u << 10);
constexpr size_t OFF_WOB = OFF_WVB + (512u << 10);
constexpr size_t OFF_W1B = 10u << 20;               // 2 MB
constexpr size_t OFF_W2B = 12u << 20;               // 2 MB
constexpr size_t OFF_Q   = 14u << 20;               // 8 MB
constexpr size_t OFF_K   = 22u << 20;               // 8 MB
constexpr size_t OFF_VT  = 30u << 20;               // 8 MB
constexpr size_t OFF_CTX = 38u << 20;               // 8 MB
constexpr size_t OFF_Y   = 46u << 20;               // 16 MB fp32 (shared y1/y2)
constexpr size_t OFF_H   = 62u << 20;               // 16 MB fp32
constexpr size_t OFF_HB  = 78u << 20;               // 8 MB bf16
constexpr size_t OFF_M1B = 86u << 20;               // 32 MB bf16 [8192,2048]
// total 118 MB

extern "C" void kernel_launch(void* const* d_in, const int* in_sizes, int n_in,
                              void* d_out, int out_size, void* d_ws, size_t ws_size,
                              hipStream_t stream) {
  const float* x  = (const float*)d_in[0];
  const float* Wq = (const float*)d_in[1];
  const float* Wk = (const float*)d_in[2];
  const float* Wv = (const float*)d_in[3];
  const float* Wo = (const float*)d_in[4];
  const float* W1 = (const float*)d_in[5];
  const float* b1 = (const float*)d_in[6];
  const float* W2 = (const float*)d_in[7];
  const float* b2 = (const float*)d_in[8];
  const float* g1 = (const float*)d_in[9];
  const float* bb1 = (const float*)d_in[10];
  const float* g2 = (const float*)d_in[11];
  const float* bb2 = (const float*)d_in[12];

  char* ws = (char*)d_ws;
  u16* xb  = (u16*)(ws + OFF_XB);
  u16* wqb = (u16*)(ws + OFF_WQB);
  u16* wkb = (u16*)(ws + OFF_WKB);
  u16* wvb = (u16*)(ws + OFF_WVB);
  u16* wob = (u16*)(ws + OFF_WOB);
  u16* w1b = (u16*)(ws + OFF_W1B);
  u16* w2b = (u16*)(ws + OFF_W2B);
  u16* qb  = (u16*)(ws + OFF_Q);
  u16* kb  = (u16*)(ws + OFF_K);
  u16* vtb = (u16*)(ws + OFF_VT);
  u16* ctxb = (u16*)(ws + OFF_CTX);
  float* y = (float*)(ws + OFF_Y);
  float* hf = (float*)(ws + OFF_H);
  u16* hb  = (u16*)(ws + OFF_HB);
  u16* m1b = (u16*)(ws + OFF_M1B);

  // 1. casts (x separate; 6 weights fused into one launch)
  cast4_kernel<<<(M_ROWS * D / 4 + 255) / 256, 256, 0, stream>>>(
      (const float4*)x, (ushort4*)xb, M_ROWS * D / 4);
  {
    const int n4 = (D4 * D) / 4 * 2 + (D * D) / 4 * 4;   // 786432
    cast_w_kernel<<<(n4 + 255) / 256, 256, 0, stream>>>(
        (const float4*)W1, (const float4*)W2, (const float4*)Wq, (const float4*)Wk,
        (const float4*)Wv, (const float4*)Wo,
        (ushort4*)w1b, (ushort4*)w2b, (ushort4*)wqb, (ushort4*)wkb,
        (ushort4*)wvb, (ushort4*)wob);
  }

  // 2. QKV projections (q pre-scaled by QSCALE)
  qkv_gemm<<<dim3(D / 128, M_ROWS / 128, 3), 256, 0, stream>>>(xb, wqb, wkb, wvb, qb, kb, vtb);

  // 3. attention: 256 blocks x 4 waves x 64 queries
  attn_kernel<<<B * H * S / 64 / 4, 256, 0, stream>>>(qb, kb, vtb, ctxb);

  // 4. out-proj: y = ctx @ Wo.T  (fp32)
  gemm_bt<0><<<dim3(D / 128, M_ROWS / 128), 256, 0, stream>>>(ctxb, wob, nullptr, y, M_ROWS, D, D);

  // 5. h = LN(x + y)  -> hf fp32, hb bf16
  ln_kernel<true><<<M_ROWS / 4, 256, 0, stream>>>(x, y, g1, bb1, hf, hb);

  // 6. m1 = relu(h @ W1.T + b1) -> bf16
  gemm_bt<1><<<dim3(D4 / 128, M_ROWS / 128), 256, 0, stream>>>(hb, w1b, b1, m1b, M_ROWS, D4, D);

  // 7. y = m1 @ W2.T + b2 -> fp32
  gemm_bt<2><<<dim3(D / 128, M_ROWS / 128), 256, 0, stream>>>(m1b, w2b, b2, y, M_ROWS, D, D4);

  // 8. out = LN(h + y)
  ln_kernel<false><<<M_ROWS / 4, 256, 0, stream>>>(hf, y, g2, bb2, (float*)d_out, nullptr);
}

// Round 5
// 309.827 us; speedup vs baseline: 1.8583x; 1.2882x over previous
//
#include <hip/hip_runtime.h>
#include <hip/hip_bf16.h>
#include <cstdint>
#include <cstddef>

// ---------- types ----------
typedef short bf16x8 __attribute__((ext_vector_type(8)));   // 8 bf16 (4 VGPRs) MFMA A/B frag
typedef float floatx4 __attribute__((ext_vector_type(4)));  // MFMA C/D frag
typedef unsigned short u16;

// Problem constants
constexpr int B = 4, S = 2048, D = 512, H = 8, DH = 64;
constexpr int M_ROWS = B * S;          // 8192
constexpr int D4 = 4 * D;              // 2048
// Q pre-scale: 1/sqrt(DH) * log2(e) so attention uses exp2 directly
constexpr float QSCALE = 0.18033688011112042f;

__device__ __forceinline__ u16 f2b(float f) {
  unsigned u = __builtin_bit_cast(unsigned, f);
  u += 0x7fff + ((u >> 16) & 1);       // RNE
  return (u16)(u >> 16);
}

__device__ __forceinline__ bf16x8 ldfrag(const u16* p) {
  return *reinterpret_cast<const bf16x8*>(p);
}

__device__ __forceinline__ floatx4 mfma16(bf16x8 a, bf16x8 b, floatx4 c) {
  return __builtin_amdgcn_mfma_f32_16x16x32_bf16(a, b, c, 0, 0, 0);
}

__device__ __forceinline__ ushort4 f2b4(float4 v) {
  ushort4 r;
  r.x = f2b(v.x); r.y = f2b(v.y); r.z = f2b(v.z); r.w = f2b(v.w);
  return r;
}

// async global->LDS, 16B per lane; LDS dest = wave-uniform base + lane*16
__device__ __forceinline__ void gld16(const u16* g, u16* l) {
  __builtin_amdgcn_global_load_lds(
      (const __attribute__((address_space(1))) void*)g,
      (__attribute__((address_space(3))) void*)l, 16, 0, 0);
}

// ---------- cast fp32 -> bf16, 4 elems/thread ----------
__global__ void cast4_kernel(const float4* __restrict__ in, ushort4* __restrict__ out, int n4) {
  int i = blockIdx.x * blockDim.x + threadIdx.x;
  if (i < n4) out[i] = f2b4(in[i]);
}

// ---------- fused weight casts (W1, W2, Wq, Wk, Wv, Wo) ----------
__global__ void cast_w_kernel(const float4* __restrict__ w1, const float4* __restrict__ w2,
                              const float4* __restrict__ wq, const float4* __restrict__ wk,
                              const float4* __restrict__ wv, const float4* __restrict__ wo,
                              ushort4* __restrict__ w1b, ushort4* __restrict__ w2b,
                              ushort4* __restrict__ wqb, ushort4* __restrict__ wkb,
                              ushort4* __restrict__ wvb, ushort4* __restrict__ wob) {
  int i = blockIdx.x * blockDim.x + threadIdx.x;
  constexpr int N1 = (D4 * D) / 4;     // 262144
  constexpr int NS = (D * D) / 4;      // 65536
  if (i < N1) { w1b[i] = f2b4(w1[i]); return; }
  i -= N1;
  if (i < N1) { w2b[i] = f2b4(w2[i]); return; }
  i -= N1;
  const int sel = i >> 16, off = i & (NS - 1);
  const float4* src = sel == 0 ? wq : sel == 1 ? wk : sel == 2 ? wv : wo;
  ushort4* dst = sel == 0 ? wqb : sel == 1 ? wkb : sel == 2 ? wvb : wob;
  dst[off] = f2b4(src[off]);
}

// ---------- staged GEMM  y = A @ W.T  (m97 structure) ----------
// Block tile (MI*32) x 128, BK=32, staged via global_load_lds width 16.
// LDS rows stride 32 elems (64B): staging is lane-contiguous (lane i -> +i*16B),
// frag ds_read_b128 bank groups = (l16&1)*16+quad*4 -> 8 groups x 8 lanes,
// conflict-free minimum 8 phases.
// 4 waves arranged 2(M) x 2(N); wave tile (MI*16) x 64.
// EPI 0: store fp32; EPI 1: +bias, relu, store bf16; EPI 2: +bias, store fp32
template <int EPI, int MI>
__global__ __launch_bounds__(256) void gemm_bt(
    const u16* __restrict__ A, const u16* __restrict__ W,
    const float* __restrict__ bias, void* __restrict__ out,
    int M, int N, int K) {
  __shared__ __align__(16) u16 As[MI * 32 * 32];
  __shared__ __align__(16) u16 Bs[128 * 32];
  const int wave = threadIdx.x >> 6, lane = threadIdx.x & 63;
  const int quad = lane >> 4, l16 = lane & 15;
  const int rowB = blockIdx.y * (MI * 32), colB = blockIdx.x * 128;
  const int rowW = (wave >> 1) * (MI * 16), colW = (wave & 1) * 64;

  floatx4 acc[MI][4];
#pragma unroll
  for (int i = 0; i < MI; i++)
#pragma unroll
    for (int j = 0; j < 4; j++) acc[i][j] = (floatx4){0.f,0.f,0.f,0.f};

  // staging assignment: wave stages A rows [wave*MI*8, +MI*8), B rows [wave*32, +32)
  const int arow = wave * (MI * 8);
  const int brow = wave * 32;
  const u16* gA = A + (size_t)(rowB + arow + (lane >> 2)) * K + (lane & 3) * 8;
  const u16* gB = W + (size_t)(colB + brow + (lane >> 2)) * K + (lane & 3) * 8;
  u16* lA = As + arow * 32;
  u16* lB = Bs + brow * 32;

  for (int kc = 0; kc < K; kc += 32) {
#pragma unroll
    for (int rr = 0; rr < MI / 2; rr++)
      gld16(gA + (size_t)rr * 16 * K + kc, lA + rr * 16 * 32);
#pragma unroll
    for (int rr = 0; rr < 2; rr++)
      gld16(gB + (size_t)rr * 16 * K + kc, lB + rr * 16 * 32);
    __syncthreads();   // drains vmcnt -> staged data visible

    bf16x8 a[MI], b[4];
#pragma unroll
    for (int i = 0; i < MI; i++)
      a[i] = ldfrag(&As[(rowW + i * 16 + l16) * 32 + quad * 8]);
#pragma unroll
    for (int j = 0; j < 4; j++)
      b[j] = ldfrag(&Bs[(colW + j * 16 + l16) * 32 + quad * 8]);
#pragma unroll
    for (int i = 0; i < MI; i++)
#pragma unroll
      for (int j = 0; j < 4; j++) acc[i][j] = mfma16(a[i], b[j], acc[i][j]);
    __syncthreads();   // ds_reads done before restage
  }

#pragma unroll
  for (int i = 0; i < MI; i++) {
#pragma unroll
    for (int j = 0; j < 4; j++) {
      const int gn = colB + colW + j * 16 + l16;
      const float bv = (EPI == 1 || EPI == 2) ? bias[gn] : 0.f;
#pragma unroll
      for (int r = 0; r < 4; r++) {
        const int gm = rowB + rowW + i * 16 + quad * 4 + r;
        float v = acc[i][j][r] + bv;
        if (EPI == 0) {
          ((float*)out)[(size_t)gm * N + gn] = v;
        } else if (EPI == 1) {
          v = v > 0.f ? v : 0.f;
          ((u16*)out)[(size_t)gm * N + gn] = f2b(v);
        } else {
          ((float*)out)[(size_t)gm * N + gn] = v;
        }
      }
    }
  }
}

// ---------- staged fused QKV GEMM (same structure, MI=4, scatter epilogue) ----------
// z: 0->q [B,H,S,DH] (pre-scaled by QSCALE), 1->k [B,H,S,DH], 2->vT [B,H,DH,S]
__global__ __launch_bounds__(256) void qkv_gemm(
    const u16* __restrict__ xb,
    const u16* __restrict__ wq, const u16* __restrict__ wk, const u16* __restrict__ wv,
    u16* __restrict__ q, u16* __restrict__ k, u16* __restrict__ vT) {
  __shared__ __align__(16) u16 As[128 * 32];
  __shared__ __align__(16) u16 Bs[128 * 32];
  const int which = blockIdx.z;
  const u16* __restrict__ W = which == 0 ? wq : (which == 1 ? wk : wv);
  const int wave = threadIdx.x >> 6, lane = threadIdx.x & 63;
  const int quad = lane >> 4, l16 = lane & 15;
  const int rowB = blockIdx.y * 128, colB = blockIdx.x * 128;
  const int rowW = (wave >> 1) * 64, colW = (wave & 1) * 64;

  floatx4 acc[4][4];
#pragma unroll
  for (int i = 0; i < 4; i++)
#pragma unroll
    for (int j = 0; j < 4; j++) acc[i][j] = (floatx4){0.f,0.f,0.f,0.f};

  const int srow = wave * 32;
  const u16* gA = xb + (size_t)(rowB + srow + (lane >> 2)) * D + (lane & 3) * 8;
  const u16* gB = W + (size_t)(colB + srow + (lane >> 2)) * D + (lane & 3) * 8;
  u16* lA = As + srow * 32;
  u16* lB = Bs + srow * 32;

  for (int kc = 0; kc < D; kc += 32) {
#pragma unroll
    for (int rr = 0; rr < 2; rr++) {
      gld16(gA + (size_t)rr * 16 * D + kc, lA + rr * 16 * 32);
      gld16(gB + (size_t)rr * 16 * D + kc, lB + rr * 16 * 32);
    }
    __syncthreads();

    bf16x8 a[4], b[4];
#pragma unroll
    for (int i = 0; i < 4; i++)
      a[i] = ldfrag(&As[(rowW + i * 16 + l16) * 32 + quad * 8]);
#pragma unroll
    for (int j = 0; j < 4; j++)
      b[j] = ldfrag(&Bs[(colW + j * 16 + l16) * 32 + quad * 8]);
#pragma unroll
    for (int i = 0; i < 4; i++)
#pragma unroll
      for (int j = 0; j < 4; j++) acc[i][j] = mfma16(a[i], b[j], acc[i][j]);
    __syncthreads();
  }

  const float oscale = (which == 0) ? QSCALE : 1.0f;
  u16* dst01 = which == 0 ? q : k;
#pragma unroll
  for (int i = 0; i < 4; i++) {
#pragma unroll
    for (int j = 0; j < 4; j++) {
      const int gn = colB + colW + j * 16 + l16;   // output feature = h*64+dh
      const int h = gn >> 6, dh = gn & 63;
#pragma unroll
      for (int r = 0; r < 4; r++) {
        const int gm = rowB + rowW + i * 16 + quad * 4 + r;   // b*S + s
        const int bb = gm >> 11, s = gm & 2047;
        const u16 val = f2b(acc[i][j][r] * oscale);
        if (which < 2) {
          dst01[((((size_t)bb * H + h) * S) + s) * DH + dh] = val;
        } else {
          vT[((((size_t)bb * H + h) * DH) + dh) * S + s] = val;
        }
      }
    }
  }
}

// ---------- fused flash attention: 64 queries per wave, no-max softmax ----------
// (unchanged from R4 — 92 us, L2-traffic model validated)
constexpr int PSTRIDE = 72;  // u16 units; 144 B rows, 16B-aligned for ds_read_b128

__global__ __launch_bounds__(256) void attn_kernel(
    const u16* __restrict__ q, const u16* __restrict__ k,
    const u16* __restrict__ vT, u16* __restrict__ ctxb) {
  __shared__ __align__(16) u16 plds[4][64 * PSTRIDE];   // 36.9 KB: per-wave 64x64 P tile
  const int wave = threadIdx.x >> 6, lane = threadIdx.x & 63;
  const int quad = lane >> 4, l16 = lane & 15;
  const int blk = (blockIdx.x & 7) * 32 + (blockIdx.x >> 3);
  const int w = blk * 4 + wave;     // 1024 wave ids
  const int bh = w >> 5;            // 32 waves (64q each) per (b,h)
  const int qt = w & 31;            // 64-query tile index within bh
  const int bb = bh >> 3, h = bh & 7;

  const u16* qp = q + ((size_t)bh * S + qt * 64 + l16) * DH + quad * 8;
  bf16x8 qf[4][2];
#pragma unroll
  for (int t = 0; t < 4; t++) {
    qf[t][0] = ldfrag(qp + (size_t)t * 16 * DH);
    qf[t][1] = ldfrag(qp + (size_t)t * 16 * DH + 32);
  }
  const u16* kbase = k + (size_t)bh * S * DH + (size_t)l16 * DH + quad * 8;
  const u16* vbase = vT + (size_t)bh * DH * S + (size_t)l16 * S + quad * 8;

  floatx4 o[4][4];
#pragma unroll
  for (int t = 0; t < 4; t++)
#pragma unroll
    for (int c = 0; c < 4; c++) o[t][c] = (floatx4){0.f,0.f,0.f,0.f};
  float lacc[4][4];
#pragma unroll
  for (int t = 0; t < 4; t++)
#pragma unroll
    for (int r = 0; r < 4; r++) lacc[t][r] = 0.f;

  u16* myp = plds[wave];
  u16* wp = myp + (quad * 4) * PSTRIDE + l16;
  const u16* rp = myp + l16 * PSTRIDE + quad * 8;

  for (int kt = 0; kt < S; kt += 64) {
    const u16* kp = kbase + (size_t)kt * DH;
    bf16x8 kf[8];
#pragma unroll
    for (int i = 0; i < 4; i++) {
      kf[2 * i]     = ldfrag(kp + (size_t)i * 16 * DH);
      kf[2 * i + 1] = ldfrag(kp + (size_t)i * 16 * DH + 32);
    }
    const u16* vp = vbase + kt;
    bf16x8 vf[8];
#pragma unroll
    for (int c = 0; c < 4; c++) {
      vf[2 * c]     = ldfrag(vp + (size_t)c * 16 * S);
      vf[2 * c + 1] = ldfrag(vp + (size_t)c * 16 * S + 32);
    }

    floatx4 sc[4][4];
#pragma unroll
    for (int t = 0; t < 4; t++)
#pragma unroll
      for (int i = 0; i < 4; i++) {
        floatx4 z = (floatx4){0.f,0.f,0.f,0.f};
        z = mfma16(qf[t][0], kf[2 * i], z);
        z = mfma16(qf[t][1], kf[2 * i + 1], z);
        sc[t][i] = z;
      }

#pragma unroll
    for (int t = 0; t < 4; t++)
#pragma unroll
      for (int r = 0; r < 4; r++) {
        float acc = 0.f;
#pragma unroll
        for (int i = 0; i < 4; i++) {
          const float p = __builtin_amdgcn_exp2f(sc[t][i][r]);
          acc += p;
          wp[(t * 16 + r) * PSTRIDE + i * 16] = f2b(p);
        }
        lacc[t][r] += acc;
      }

#pragma unroll
    for (int t = 0; t < 4; t++) {
      const bf16x8 pf0 = *reinterpret_cast<const bf16x8*>(rp + (size_t)t * 16 * PSTRIDE);
      const bf16x8 pf1 = *reinterpret_cast<const bf16x8*>(rp + (size_t)t * 16 * PSTRIDE + 32);
#pragma unroll
      for (int c = 0; c < 4; c++) {
        o[t][c] = mfma16(pf0, vf[2 * c], o[t][c]);
        o[t][c] = mfma16(pf1, vf[2 * c + 1], o[t][c]);
      }
    }
  }

  float inv[4][4];
#pragma unroll
  for (int t = 0; t < 4; t++)
#pragma unroll
    for (int r = 0; r < 4; r++) {
      float l = lacc[t][r];
#pragma unroll
      for (int d = 1; d < 16; d <<= 1) l += __shfl_xor(l, d);
      inv[t][r] = 1.0f / l;
    }

  const size_t crow_base = ((size_t)bb * S) * D + h * DH;
#pragma unroll
  for (int t = 0; t < 4; t++)
#pragma unroll
    for (int c = 0; c < 4; c++) {
      const int dh = c * 16 + l16;
#pragma unroll
      for (int r = 0; r < 4; r++) {
        const int s = qt * 64 + t * 16 + quad * 4 + r;
        ctxb[crow_base + (size_t)s * D + dh] = f2b(o[t][c][r] * inv[t][r]);
      }
    }
}

// ---------- layernorm: out = LN(resid + y) ----------
template <bool BF16OUT>
__global__ __launch_bounds__(256) void ln_kernel(
    const float* __restrict__ resid, const float* __restrict__ y,
    const float* __restrict__ g, const float* __restrict__ bvec,
    float* __restrict__ outF, u16* __restrict__ outB) {
  const int wave = threadIdx.x >> 6, lane = threadIdx.x & 63;
  const int row = blockIdx.x * 4 + wave;
  const float* rp = resid + (size_t)row * D + lane * 8;
  const float* yp = y + (size_t)row * D + lane * 8;
  float v[8];
  const float4 a0 = *(const float4*)rp, a1 = *(const float4*)(rp + 4);
  const float4 b0 = *(const float4*)yp, b1 = *(const float4*)(yp + 4);
  v[0] = a0.x + b0.x; v[1] = a0.y + b0.y; v[2] = a0.z + b0.z; v[3] = a0.w + b0.w;
  v[4] = a1.x + b1.x; v[5] = a1.y + b1.y; v[6] = a1.z + b1.z; v[7] = a1.w + b1.w;
  float sum = 0.f;
#pragma unroll
  for (int i = 0; i < 8; i++) sum += v[i];
#pragma unroll
  for (int d = 1; d < 64; d <<= 1) sum += __shfl_xor(sum, d);
  const float mu = sum * (1.f / D);
  float vs = 0.f;
#pragma unroll
  for (int i = 0; i < 8; i++) { const float t = v[i] - mu; vs += t * t; }
#pragma unroll
  for (int d = 1; d < 64; d <<= 1) vs += __shfl_xor(vs, d);
  const float rstd = rsqrtf(vs * (1.f / D) + 1e-5f);
#pragma unroll
  for (int i = 0; i < 8; i++) {
    const int col = lane * 8 + i;
    const float o = (v[i] - mu) * rstd * g[col] + bvec[col];
    outF[(size_t)row * D + col] = o;
    if (BF16OUT) outB[(size_t)row * D + col] = f2b(o);
  }
}

// ---------- workspace layout (bytes) ----------
constexpr size_t OFF_XB  = 0;                       // 8 MB  xb [8192,512] bf16
constexpr size_t OFF_WQB = 8u << 20;                // 512 KB
constexpr size_t OFF_WKB = OFF_WQB + (512u << 10);
constexpr size_t OFF_WVB = OFF_WKB + (512u << 10);
constexpr size_t OFF_WOB = OFF_WVB + (512u << 10);
constexpr size_t OFF_W1B = 10u << 20;               // 2 MB
constexpr size_t OFF_W2B = 12u << 20;               // 2 MB
constexpr size_t OFF_Q   = 14u << 20;               // 8 MB
constexpr size_t OFF_K   = 22u << 20;               // 8 MB
constexpr size_t OFF_VT  = 30u << 20;               // 8 MB
constexpr size_t OFF_CTX = 38u << 20;               // 8 MB
constexpr size_t OFF_Y   = 46u << 20;               // 16 MB fp32 (shared y1/y2)
constexpr size_t OFF_H   = 62u << 20;               // 16 MB fp32
constexpr size_t OFF_HB  = 78u << 20;               // 8 MB bf16
constexpr size_t OFF_M1B = 86u << 20;               // 32 MB bf16 [8192,2048]
// total 118 MB

extern "C" void kernel_launch(void* const* d_in, const int* in_sizes, int n_in,
                              void* d_out, int out_size, void* d_ws, size_t ws_size,
                              hipStream_t stream) {
  const float* x  = (const float*)d_in[0];
  const float* Wq = (const float*)d_in[1];
  const float* Wk = (const float*)d_in[2];
  const float* Wv = (const float*)d_in[3];
  const float* Wo = (const float*)d_in[4];
  const float* W1 = (const float*)d_in[5];
  const float* b1 = (const float*)d_in[6];
  const float* W2 = (const float*)d_in[7];
  const float* b2 = (const float*)d_in[8];
  const float* g1 = (const float*)d_in[9];
  const float* bb1 = (const float*)d_in[10];
  const float* g2 = (const float*)d_in[11];
  const float* bb2 = (const float*)d_in[12];

  char* ws = (char*)d_ws;
  u16* xb  = (u16*)(ws + OFF_XB);
  u16* wqb = (u16*)(ws + OFF_WQB);
  u16* wkb = (u16*)(ws + OFF_WKB);
  u16* wvb = (u16*)(ws + OFF_WVB);
  u16* wob = (u16*)(ws + OFF_WOB);
  u16* w1b = (u16*)(ws + OFF_W1B);
  u16* w2b = (u16*)(ws + OFF_W2B);
  u16* qb  = (u16*)(ws + OFF_Q);
  u16* kb  = (u16*)(ws + OFF_K);
  u16* vtb = (u16*)(ws + OFF_VT);
  u16* ctxb = (u16*)(ws + OFF_CTX);
  float* y = (float*)(ws + OFF_Y);
  float* hf = (float*)(ws + OFF_H);
  u16* hb  = (u16*)(ws + OFF_HB);
  u16* m1b = (u16*)(ws + OFF_M1B);

  // 1. casts
  cast4_kernel<<<(M_ROWS * D / 4 + 255) / 256, 256, 0, stream>>>(
      (const float4*)x, (ushort4*)xb, M_ROWS * D / 4);
  {
    const int n4 = (D4 * D) / 4 * 2 + (D * D) / 4 * 4;   // 786432
    cast_w_kernel<<<(n4 + 255) / 256, 256, 0, stream>>>(
        (const float4*)W1, (const float4*)W2, (const float4*)Wq, (const float4*)Wk,
        (const float4*)Wv, (const float4*)Wo,
        (ushort4*)w1b, (ushort4*)w2b, (ushort4*)wqb, (ushort4*)wkb,
        (ushort4*)wvb, (ushort4*)wob);
  }

  // 2. QKV projections (staged; q pre-scaled by QSCALE); 768 blocks ~3/CU
  qkv_gemm<<<dim3(D / 128, M_ROWS / 128, 3), 256, 0, stream>>>(xb, wqb, wkb, wvb, qb, kb, vtb);

  // 3. attention: 256 blocks x 4 waves x 64 queries
  attn_kernel<<<B * H * S / 64 / 4, 256, 0, stream>>>(qb, kb, vtb, ctxb);

  // 4. out-proj: y = ctx @ Wo.T (fp32); MI=2 -> 64x128 tiles, 512 blocks (2/CU)
  gemm_bt<0, 2><<<dim3(D / 128, M_ROWS / 64), 256, 0, stream>>>(
      ctxb, wob, nullptr, y, M_ROWS, D, D);

  // 5. h = LN(x + y)  -> hf fp32, hb bf16
  ln_kernel<true><<<M_ROWS / 4, 256, 0, stream>>>(x, y, g1, bb1, hf, hb);

  // 6. m1 = relu(h @ W1.T + b1) -> bf16; MI=4, 1024 blocks (4/CU)
  gemm_bt<1, 4><<<dim3(D4 / 128, M_ROWS / 128), 256, 0, stream>>>(
      hb, w1b, b1, m1b, M_ROWS, D4, D);

  // 7. y = m1 @ W2.T + b2 -> fp32; MI=2, 512 blocks (2/CU)
  gemm_bt<2, 2><<<dim3(D / 128, M_ROWS / 64), 256, 0, stream>>>(
      m1b, w2b, b2, y, M_ROWS, D, D4);

  // 8. out = LN(h + y)
  ln_kernel<false><<<M_ROWS / 4, 256, 0, stream>>>(hf, y, g2, bb2, (float*)d_out, nullptr);
}

// Round 7
// 304.115 us; speedup vs baseline: 1.8932x; 1.0188x over previous
//
#include <hip/hip_runtime.h>
#include <hip/hip_bf16.h>
#include <cstdint>
#include <cstddef>

// ---------- types ----------
typedef short bf16x8 __attribute__((ext_vector_type(8)));   // 8 bf16 (4 VGPRs) MFMA A/B frag
typedef float floatx4 __attribute__((ext_vector_type(4)));  // MFMA C/D frag
typedef unsigned short u16;

// Problem constants
constexpr int B = 4, S = 2048, D = 512, H = 8, DH = 64;
constexpr int M_ROWS = B * S;          // 8192
constexpr int D4 = 4 * D;              // 2048
// Q pre-scale: 1/sqrt(DH) * log2(e) so attention uses exp2 directly
constexpr float QSCALE = 0.18033688011112042f;

__device__ __forceinline__ u16 f2b(float f) {
  unsigned u = __builtin_bit_cast(unsigned, f);
  u += 0x7fff + ((u >> 16) & 1);       // RNE
  return (u16)(u >> 16);
}

__device__ __forceinline__ bf16x8 ldfrag(const u16* p) {
  return *reinterpret_cast<const bf16x8*>(p);
}

__device__ __forceinline__ floatx4 mfma16(bf16x8 a, bf16x8 b, floatx4 c) {
  return __builtin_amdgcn_mfma_f32_16x16x32_bf16(a, b, c, 0, 0, 0);
}

__device__ __forceinline__ ushort4 f2b4(float4 v) {
  ushort4 r;
  r.x = f2b(v.x); r.y = f2b(v.y); r.z = f2b(v.z); r.w = f2b(v.w);
  return r;
}

// async global->LDS, 16B per lane; LDS dest = wave-uniform base + lane*16
__device__ __forceinline__ void gld16(const u16* g, u16* l) {
  __builtin_amdgcn_global_load_lds(
      (const __attribute__((address_space(1))) void*)g,
      (__attribute__((address_space(3))) void*)l, 16, 0, 0);
}

// ---------- cast fp32 -> bf16, 4 elems/thread ----------
__global__ void cast4_kernel(const float4* __restrict__ in, ushort4* __restrict__ out, int n4) {
  int i = blockIdx.x * blockDim.x + threadIdx.x;
  if (i < n4) out[i] = f2b4(in[i]);
}

// ---------- fused weight casts (W1, W2, Wq, Wk, Wv, Wo) ----------
__global__ void cast_w_kernel(const float4* __restrict__ w1, const float4* __restrict__ w2,
                              const float4* __restrict__ wq, const float4* __restrict__ wk,
                              const float4* __restrict__ wv, const float4* __restrict__ wo,
                              ushort4* __restrict__ w1b, ushort4* __restrict__ w2b,
                              ushort4* __restrict__ wqb, ushort4* __restrict__ wkb,
                              ushort4* __restrict__ wvb, ushort4* __restrict__ wob) {
  int i = blockIdx.x * blockDim.x + threadIdx.x;
  constexpr int N1 = (D4 * D) / 4;     // 262144
  constexpr int NS = (D * D) / 4;      // 65536
  if (i < N1) { w1b[i] = f2b4(w1[i]); return; }
  i -= N1;
  if (i < N1) { w2b[i] = f2b4(w2[i]); return; }
  i -= N1;
  const int sel = i >> 16, off = i & (NS - 1);
  const float4* src = sel == 0 ? wq : sel == 1 ? wk : sel == 2 ? wv : wo;
  ushort4* dst = sel == 0 ? wqb : sel == 1 ? wkb : sel == 2 ? wvb : wob;
  dst[off] = f2b4(src[off]);
}

// ---------- staged GEMM  y = A @ W.T, BK=64 (two 32-col panels), optional split-K ----------
// Block tile 128x128; 4 waves 2(M)x2(N), wave tile 64x64.
// LDS panels [2][128][32] u16: staging lane-contiguous (16 rows x 32 cols per gld16),
// frag ds_read_b128 bank groups = (l16&1)*16+quad*4 (8 groups) — conflict-free minimum.
// blockIdx.z selects K-half [z*klen, (z+1)*klen) and output buffer out0/out1.
// EPI 0: store fp32 (no bias); EPI 1: +bias, relu, store bf16
template <int EPI>
__global__ __launch_bounds__(256) void gemm_bt(
    const u16* __restrict__ A, const u16* __restrict__ W,
    const float* __restrict__ bias, void* __restrict__ out0, void* __restrict__ out1,
    int M, int N, int K, int klen) {
  __shared__ __align__(16) u16 As[2 * 128 * 32];
  __shared__ __align__(16) u16 Bs[2 * 128 * 32];
  const int wave = threadIdx.x >> 6, lane = threadIdx.x & 63;
  const int quad = lane >> 4, l16 = lane & 15;
  const int rowB = blockIdx.y * 128, colB = blockIdx.x * 128;
  const int rowW = (wave >> 1) * 64, colW = (wave & 1) * 64;
  const int koff = blockIdx.z * klen;
  void* out = blockIdx.z ? out1 : out0;

  floatx4 acc[4][4];
#pragma unroll
  for (int i = 0; i < 4; i++)
#pragma unroll
    for (int j = 0; j < 4; j++) acc[i][j] = (floatx4){0.f,0.f,0.f,0.f};

  // staging: wave w covers rows [w*32, w*32+32) of both A and B tiles;
  // per gld16: 16 rows x 32 cols (lane>>2 = row, lane&3 = 8-elem col chunk)
  const u16* gA = A + (size_t)(rowB + wave * 32 + (lane >> 2)) * K + koff + (lane & 3) * 8;
  const u16* gB = W + (size_t)(colB + wave * 32 + (lane >> 2)) * K + koff + (lane & 3) * 8;
  u16* lA = As + (wave * 32) * 32;
  u16* lB = Bs + (wave * 32) * 32;

  for (int kc = 0; kc < klen; kc += 64) {
#pragma unroll
    for (int kk = 0; kk < 2; kk++)
#pragma unroll
      for (int rr = 0; rr < 2; rr++) {
        gld16(gA + (size_t)rr * 16 * K + kc + kk * 32, lA + kk * 4096 + rr * 16 * 32);
        gld16(gB + (size_t)rr * 16 * K + kc + kk * 32, lB + kk * 4096 + rr * 16 * 32);
      }
    __syncthreads();   // drains vmcnt -> staged data visible

#pragma unroll
    for (int kk = 0; kk < 2; kk++) {
      bf16x8 a[4], b[4];
#pragma unroll
      for (int i = 0; i < 4; i++)
        a[i] = ldfrag(&As[kk * 4096 + (rowW + i * 16 + l16) * 32 + quad * 8]);
#pragma unroll
      for (int j = 0; j < 4; j++)
        b[j] = ldfrag(&Bs[kk * 4096 + (colW + j * 16 + l16) * 32 + quad * 8]);
#pragma unroll
      for (int i = 0; i < 4; i++)
#pragma unroll
        for (int j = 0; j < 4; j++) acc[i][j] = mfma16(a[i], b[j], acc[i][j]);
    }
    __syncthreads();   // ds_reads done before restage
  }

#pragma unroll
  for (int i = 0; i < 4; i++) {
#pragma unroll
    for (int j = 0; j < 4; j++) {
      const int gn = colB + colW + j * 16 + l16;
      const float bv = (EPI == 1) ? bias[gn] : 0.f;
#pragma unroll
      for (int r = 0; r < 4; r++) {
        const int gm = rowB + rowW + i * 16 + quad * 4 + r;
        float v = acc[i][j][r] + bv;
        if (EPI == 0) {
          ((float*)out)[(size_t)gm * N + gn] = v;
        } else {
          v = v > 0.f ? v : 0.f;
          ((u16*)out)[(size_t)gm * N + gn] = f2b(v);
        }
      }
    }
  }
}

// ---------- staged fused QKV GEMM (BK=64, scatter epilogue) ----------
// z: 0->q [B,H,S,DH] (pre-scaled by QSCALE), 1->k [B,H,S,DH], 2->vT [B,H,DH,S]
__global__ __launch_bounds__(256) void qkv_gemm(
    const u16* __restrict__ xb,
    const u16* __restrict__ wq, const u16* __restrict__ wk, const u16* __restrict__ wv,
    u16* __restrict__ q, u16* __restrict__ k, u16* __restrict__ vT) {
  __shared__ __align__(16) u16 As[2 * 128 * 32];
  __shared__ __align__(16) u16 Bs[2 * 128 * 32];
  const int which = blockIdx.z;
  const u16* __restrict__ W = which == 0 ? wq : (which == 1 ? wk : wv);
  const int wave = threadIdx.x >> 6, lane = threadIdx.x & 63;
  const int quad = lane >> 4, l16 = lane & 15;
  const int rowB = blockIdx.y * 128, colB = blockIdx.x * 128;
  const int rowW = (wave >> 1) * 64, colW = (wave & 1) * 64;

  floatx4 acc[4][4];
#pragma unroll
  for (int i = 0; i < 4; i++)
#pragma unroll
    for (int j = 0; j < 4; j++) acc[i][j] = (floatx4){0.f,0.f,0.f,0.f};

  const u16* gA = xb + (size_t)(rowB + wave * 32 + (lane >> 2)) * D + (lane & 3) * 8;
  const u16* gB = W + (size_t)(colB + wave * 32 + (lane >> 2)) * D + (lane & 3) * 8;
  u16* lA = As + (wave * 32) * 32;
  u16* lB = Bs + (wave * 32) * 32;

  for (int kc = 0; kc < D; kc += 64) {
#pragma unroll
    for (int kk = 0; kk < 2; kk++)
#pragma unroll
      for (int rr = 0; rr < 2; rr++) {
        gld16(gA + (size_t)rr * 16 * D + kc + kk * 32, lA + kk * 4096 + rr * 16 * 32);
        gld16(gB + (size_t)rr * 16 * D + kc + kk * 32, lB + kk * 4096 + rr * 16 * 32);
      }
    __syncthreads();

#pragma unroll
    for (int kk = 0; kk < 2; kk++) {
      bf16x8 a[4], b[4];
#pragma unroll
      for (int i = 0; i < 4; i++)
        a[i] = ldfrag(&As[kk * 4096 + (rowW + i * 16 + l16) * 32 + quad * 8]);
#pragma unroll
      for (int j = 0; j < 4; j++)
        b[j] = ldfrag(&Bs[kk * 4096 + (colW + j * 16 + l16) * 32 + quad * 8]);
#pragma unroll
      for (int i = 0; i < 4; i++)
#pragma unroll
        for (int j = 0; j < 4; j++) acc[i][j] = mfma16(a[i], b[j], acc[i][j]);
    }
    __syncthreads();
  }

  const float oscale = (which == 0) ? QSCALE : 1.0f;
  u16* dst01 = which == 0 ? q : k;
#pragma unroll
  for (int i = 0; i < 4; i++) {
#pragma unroll
    for (int j = 0; j < 4; j++) {
      const int gn = colB + colW + j * 16 + l16;   // output feature = h*64+dh
      const int h = gn >> 6, dh = gn & 63;
#pragma unroll
      for (int r = 0; r < 4; r++) {
        const int gm = rowB + rowW + i * 16 + quad * 4 + r;   // b*S + s
        const int bb = gm >> 11, s = gm & 2047;
        const u16 val = f2b(acc[i][j][r] * oscale);
        if (which < 2) {
          dst01[((((size_t)bb * H + h) * S) + s) * DH + dh] = val;
        } else {
          vT[((((size_t)bb * H + h) * DH) + dh) * S + s] = val;
        }
      }
    }
  }
}

// ---------- fused flash attention: 64q per wave-pair, keys split 2 ways ----------
// Block = 8 waves (512 thr) = 4 q-tiles x 2 key-halves. With no-max softmax the
// key-split partials are exactly additive: O += O', l += l' (LDS combine at end).
// 2 waves/SIMD -> MFMA/VALU/load stalls of one wave overlap the other (m114).
// Combine buffers OVERLAY the pair's dead P-tiles after the K loop:
// per-pair slab plds[2p..2p+1] = 18432 B >= 64*64*4 (O) + 64*4 (l) = 16640 B.
constexpr int PSTRIDE = 72;  // u16 units; 144 B rows, 16B-aligned for ds_read_b128

__global__ __launch_bounds__(512) void attn_kernel(
    const u16* __restrict__ q, const u16* __restrict__ k,
    const u16* __restrict__ vT, u16* __restrict__ ctxb) {
  __shared__ __align__(16) u16 plds[8][64 * PSTRIDE];   // 73.7 KB P tiles
  const int wave = threadIdx.x >> 6, lane = threadIdx.x & 63;
  const int quad = lane >> 4, l16 = lane & 15;
  const int pair = wave >> 1, khalf = wave & 1;
  // XCD swizzle: 256 blocks; HW sends block b to XCD b%8; contiguous q-tile
  // runs per XCD keep each (b,h)'s 512KB K/V resident in that XCD's L2.
  const int blk = (blockIdx.x & 7) * 32 + (blockIdx.x >> 3);
  const int w = blk * 4 + pair;     // q-tile id (1024 total)
  const int bh = w >> 5;            // 32 q-tiles (64q) per (b,h)
  const int qt = w & 31;
  const int bb = bh >> 3, h = bh & 7;

  const u16* qp = q + ((size_t)bh * S + qt * 64 + l16) * DH + quad * 8;
  bf16x8 qf[4][2];
#pragma unroll
  for (int t = 0; t < 4; t++) {
    qf[t][0] = ldfrag(qp + (size_t)t * 16 * DH);
    qf[t][1] = ldfrag(qp + (size_t)t * 16 * DH + 32);
  }
  const u16* kbase = k + (size_t)bh * S * DH + (size_t)(khalf * 1024 + l16) * DH + quad * 8;
  const u16* vbase = vT + (size_t)bh * DH * S + (size_t)l16 * S + khalf * 1024 + quad * 8;

  floatx4 o[4][4];
#pragma unroll
  for (int t = 0; t < 4; t++)
#pragma unroll
    for (int c = 0; c < 4; c++) o[t][c] = (floatx4){0.f,0.f,0.f,0.f};
  float lacc[4][4];
#pragma unroll
  for (int t = 0; t < 4; t++)
#pragma unroll
    for (int r = 0; r < 4; r++) lacc[t][r] = 0.f;

  u16* myp = plds[wave];
  u16* wp = myp + (quad * 4) * PSTRIDE + l16;
  const u16* rp = myp + l16 * PSTRIDE + quad * 8;

  for (int kt = 0; kt < S / 2; kt += 64) {
    const u16* kp = kbase + (size_t)kt * DH;
    bf16x8 kf[8];
#pragma unroll
    for (int i = 0; i < 4; i++) {
      kf[2 * i]     = ldfrag(kp + (size_t)i * 16 * DH);
      kf[2 * i + 1] = ldfrag(kp + (size_t)i * 16 * DH + 32);
    }
    const u16* vp = vbase + kt;
    bf16x8 vf[8];
#pragma unroll
    for (int c = 0; c < 4; c++) {
      vf[2 * c]     = ldfrag(vp + (size_t)c * 16 * S);
      vf[2 * c + 1] = ldfrag(vp + (size_t)c * 16 * S + 32);
    }

    floatx4 sc[4][4];
#pragma unroll
    for (int t = 0; t < 4; t++)
#pragma unroll
      for (int i = 0; i < 4; i++) {
        floatx4 z = (floatx4){0.f,0.f,0.f,0.f};
        z = mfma16(qf[t][0], kf[2 * i], z);
        z = mfma16(qf[t][1], kf[2 * i + 1], z);
        sc[t][i] = z;
      }

#pragma unroll
    for (int t = 0; t < 4; t++)
#pragma unroll
      for (int r = 0; r < 4; r++) {
        float acc = 0.f;
#pragma unroll
        for (int i = 0; i < 4; i++) {
          const float p = __builtin_amdgcn_exp2f(sc[t][i][r]);
          acc += p;
          wp[(t * 16 + r) * PSTRIDE + i * 16] = f2b(p);
        }
        lacc[t][r] += acc;
      }

#pragma unroll
    for (int t = 0; t < 4; t++) {
      const bf16x8 pf0 = *reinterpret_cast<const bf16x8*>(rp + (size_t)t * 16 * PSTRIDE);
      const bf16x8 pf1 = *reinterpret_cast<const bf16x8*>(rp + (size_t)t * 16 * PSTRIDE + 32);
#pragma unroll
      for (int c = 0; c < 4; c++) {
        o[t][c] = mfma16(pf0, vf[2 * c], o[t][c]);
        o[t][c] = mfma16(pf1, vf[2 * c + 1], o[t][c]);
      }
    }
  }

  // per-wave l reduce across the 16 lanes sharing each row
  float lr[4][4];
#pragma unroll
  for (int t = 0; t < 4; t++)
#pragma unroll
    for (int r = 0; r < 4; r++) {
      float l = lacc[t][r];
#pragma unroll
      for (int d = 1; d < 16; d <<= 1) l += __shfl_xor(l, d);
      lr[t][r] = l;
    }

  // combine key-half partials (exactly additive: no max-rescale anywhere).
  // ob: [64 lanes][64 floats] = 16 KB, lb: 64 floats — overlaid on dead P tiles.
  float* ob = reinterpret_cast<float*>(plds[2 * pair]);
  float* lb = ob + 64 * 64;

  __syncthreads();
  if (khalf == 1) {
#pragma unroll
    for (int t = 0; t < 4; t++)
#pragma unroll
      for (int c = 0; c < 4; c++)
        *reinterpret_cast<floatx4*>(&ob[lane * 64 + (t * 4 + c) * 4]) = o[t][c];
    if (l16 == 0) {
#pragma unroll
      for (int t = 0; t < 4; t++)
#pragma unroll
        for (int r = 0; r < 4; r++) lb[t * 16 + quad * 4 + r] = lr[t][r];
    }
  }
  __syncthreads();
  if (khalf == 0) {
    float inv[4][4];
#pragma unroll
    for (int t = 0; t < 4; t++)
#pragma unroll
      for (int r = 0; r < 4; r++)
        inv[t][r] = 1.0f / (lr[t][r] + lb[t * 16 + quad * 4 + r]);

    const size_t crow_base = ((size_t)bb * S) * D + h * DH;
#pragma unroll
    for (int t = 0; t < 4; t++)
#pragma unroll
      for (int c = 0; c < 4; c++) {
        const floatx4 oo = o[t][c] +
            *reinterpret_cast<const floatx4*>(&ob[lane * 64 + (t * 4 + c) * 4]);
        const int dh = c * 16 + l16;
#pragma unroll
        for (int r = 0; r < 4; r++) {
          const int s = qt * 64 + t * 16 + quad * 4 + r;
          ctxb[crow_base + (size_t)s * D + dh] = f2b(oo[r] * inv[t][r]);
        }
      }
  }
}

// ---------- layernorm: out = LN(resid + ya + yb [+ pb]) ----------
template <bool BF16OUT, bool PB>
__global__ __launch_bounds__(256) void ln_kernel(
    const float* __restrict__ resid, const float* __restrict__ ya,
    const float* __restrict__ yb, const float* __restrict__ pb,
    const float* __restrict__ g, const float* __restrict__ bvec,
    float* __restrict__ outF, u16* __restrict__ outB) {
  const int wave = threadIdx.x >> 6, lane = threadIdx.x & 63;
  const int row = blockIdx.x * 4 + wave;
  const float* rp = resid + (size_t)row * D + lane * 8;
  const float* ap = ya + (size_t)row * D + lane * 8;
  const float* bp = yb + (size_t)row * D + lane * 8;
  float v[8];
  const float4 r0 = *(const float4*)rp, r1 = *(const float4*)(rp + 4);
  const float4 a0 = *(const float4*)ap, a1 = *(const float4*)(ap + 4);
  const float4 b0 = *(const float4*)bp, b1 = *(const float4*)(bp + 4);
  v[0] = r0.x + a0.x + b0.x; v[1] = r0.y + a0.y + b0.y;
  v[2] = r0.z + a0.z + b0.z; v[3] = r0.w + a0.w + b0.w;
  v[4] = r1.x + a1.x + b1.x; v[5] = r1.y + a1.y + b1.y;
  v[6] = r1.z + a1.z + b1.z; v[7] = r1.w + a1.w + b1.w;
  if (PB) {
    const float4 p0 = *(const float4*)(pb + lane * 8);
    const float4 p1 = *(const float4*)(pb + lane * 8 + 4);
    v[0] += p0.x; v[1] += p0.y; v[2] += p0.z; v[3] += p0.w;
    v[4] += p1.x; v[5] += p1.y; v[6] += p1.z; v[7] += p1.w;
  }
  float sum = 0.f;
#pragma unroll
  for (int i = 0; i < 8; i++) sum += v[i];
#pragma unroll
  for (int d = 1; d < 64; d <<= 1) sum += __shfl_xor(sum, d);
  const float mu = sum * (1.f / D);
  float vs = 0.f;
#pragma unroll
  for (int i = 0; i < 8; i++) { const float t = v[i] - mu; vs += t * t; }
#pragma unroll
  for (int d = 1; d < 64; d <<= 1) vs += __shfl_xor(vs, d);
  const float rstd = rsqrtf(vs * (1.f / D) + 1e-5f);
#pragma unroll
  for (int i = 0; i < 8; i++) {
    const int col = lane * 8 + i;
    const float o = (v[i] - mu) * rstd * g[col] + bvec[col];
    outF[(size_t)row * D + col] = o;
    if (BF16OUT) outB[(size_t)row * D + col] = f2b(o);
  }
}

// ---------- workspace layout (bytes) ----------
constexpr size_t OFF_XB  = 0;                       // 8 MB  xb [8192,512] bf16
constexpr size_t OFF_WQB = 8u << 20;                // 512 KB
constexpr size_t OFF_WKB = OFF_WQB + (512u << 10);
constexpr size_t OFF_WVB = OFF_WKB + (512u << 10);
constexpr size_t OFF_WOB = OFF_WVB + (512u << 10);
constexpr size_t OFF_W1B = 10u << 20;               // 2 MB
constexpr size_t OFF_W2B = 12u << 20;               // 2 MB
constexpr size_t OFF_Q   = 14u << 20;               // 8 MB   (reused as y1 fp32 after attn)
constexpr size_t OFF_K   = 22u << 20;               // 8 MB   (y1 second half)
constexpr size_t OFF_VT  = 30u << 20;               // 8 MB
constexpr size_t OFF_CTX = 38u << 20;               // 8 MB
constexpr size_t OFF_Y   = 46u << 20;               // 16 MB fp32 (y0, shared)
constexpr size_t OFF_H   = 62u << 20;               // 16 MB fp32
constexpr size_t OFF_HB  = 78u << 20;               // 8 MB bf16
constexpr size_t OFF_M1B = 86u << 20;               // 32 MB bf16 [8192,2048]
// total 118 MB

extern "C" void kernel_launch(void* const* d_in, const int* in_sizes, int n_in,
                              void* d_out, int out_size, void* d_ws, size_t ws_size,
                              hipStream_t stream) {
  const float* x  = (const float*)d_in[0];
  const float* Wq = (const float*)d_in[1];
  const float* Wk = (const float*)d_in[2];
  const float* Wv = (const float*)d_in[3];
  const float* Wo = (const float*)d_in[4];
  const float* W1 = (const float*)d_in[5];
  const float* b1 = (const float*)d_in[6];
  const float* W2 = (const float*)d_in[7];
  const float* b2 = (const float*)d_in[8];
  const float* g1 = (const float*)d_in[9];
  const float* bb1 = (const float*)d_in[10];
  const float* g2 = (const float*)d_in[11];
  const float* bb2 = (const float*)d_in[12];

  char* ws = (char*)d_ws;
  u16* xb  = (u16*)(ws + OFF_XB);
  u16* wqb = (u16*)(ws + OFF_WQB);
  u16* wkb = (u16*)(ws + OFF_WKB);
  u16* wvb = (u16*)(ws + OFF_WVB);
  u16* wob = (u16*)(ws + OFF_WOB);
  u16* w1b = (u16*)(ws + OFF_W1B);
  u16* w2b = (u16*)(ws + OFF_W2B);
  u16* qb  = (u16*)(ws + OFF_Q);
  u16* kb  = (u16*)(ws + OFF_K);
  u16* vtb = (u16*)(ws + OFF_VT);
  u16* ctxb = (u16*)(ws + OFF_CTX);
  float* y0 = (float*)(ws + OFF_Y);
  float* y1 = (float*)(ws + OFF_Q);     // reuses q/k region (free after attention)
  float* hf = (float*)(ws + OFF_H);
  u16* hb  = (u16*)(ws + OFF_HB);
  u16* m1b = (u16*)(ws + OFF_M1B);

  // 1. casts
  cast4_kernel<<<(M_ROWS * D / 4 + 255) / 256, 256, 0, stream>>>(
      (const float4*)x, (ushort4*)xb, M_ROWS * D / 4);
  {
    const int n4 = (D4 * D) / 4 * 2 + (D * D) / 4 * 4;   // 786432
    cast_w_kernel<<<(n4 + 255) / 256, 256, 0, stream>>>(
        (const float4*)W1, (const float4*)W2, (const float4*)Wq, (const float4*)Wk,
        (const float4*)Wv, (const float4*)Wo,
        (ushort4*)w1b, (ushort4*)w2b, (ushort4*)wqb, (ushort4*)wkb,
        (ushort4*)wvb, (ushort4*)wob);
  }

  // 2. QKV projections (staged BK=64; q pre-scaled by QSCALE); 768 blocks 3/CU
  qkv_gemm<<<dim3(D / 128, M_ROWS / 128, 3), 256, 0, stream>>>(xb, wqb, wkb, wvb, qb, kb, vtb);

  // 3. attention: 256 blocks x 8 waves (4 q-tiles x 2 key-halves)
  attn_kernel<<<B * H * S / 64 / 4, 512, 0, stream>>>(qb, kb, vtb, ctxb);

  // 4. out-proj: split-K=2 -> y0,y1 partials; 512 blocks 2/CU
  gemm_bt<0><<<dim3(D / 128, M_ROWS / 128, 2), 256, 0, stream>>>(
      ctxb, wob, nullptr, y0, y1, M_ROWS, D, D, D / 2);

  // 5. h = LN(x + y0 + y1)  -> hf fp32, hb bf16
  ln_kernel<true, false><<<M_ROWS / 4, 256, 0, stream>>>(
      x, y0, y1, nullptr, g1, bb1, hf, hb);

  // 6. m1 = relu(h @ W1.T + b1) -> bf16; 1024 blocks 4/CU
  gemm_bt<1><<<dim3(D4 / 128, M_ROWS / 128, 1), 256, 0, stream>>>(
      hb, w1b, b1, m1b, nullptr, M_ROWS, D4, D, D);

  // 7. mlp partials: split-K=2 over K=2048 -> y0,y1; 512 blocks 2/CU
  gemm_bt<0><<<dim3(D / 128, M_ROWS / 128, 2), 256, 0, stream>>>(
      m1b, w2b, nullptr, y0, y1, M_ROWS, D, D4, D4 / 2);

  // 8. out = LN(h + y0 + y1 + b2)   (b2 folded in as pre-bias)
  ln_kernel<false, true><<<M_ROWS / 4, 256, 0, stream>>>(
      hf, y0, y1, b2, g2, bb2, (float*)d_out, nullptr);
}

// Round 8
// 285.978 us; speedup vs baseline: 2.0133x; 1.0634x over previous
//
#include <hip/hip_runtime.h>
#include <hip/hip_bf16.h>
#include <cstdint>
#include <cstddef>

// ---------- types ----------
typedef short bf16x8 __attribute__((ext_vector_type(8)));   // 8 bf16 (4 VGPRs) MFMA A/B frag
typedef float floatx4 __attribute__((ext_vector_type(4)));  // MFMA C/D frag
typedef unsigned short u16;

// Problem constants
constexpr int B = 4, S = 2048, D = 512, H = 8, DH = 64;
constexpr int M_ROWS = B * S;          // 8192
constexpr int D4 = 4 * D;              // 2048
// Q pre-scale: 1/sqrt(DH) * log2(e) so attention uses exp2 directly
constexpr float QSCALE = 0.18033688011112042f;

__device__ __forceinline__ u16 f2b(float f) {
  unsigned u = __builtin_bit_cast(unsigned, f);
  u += 0x7fff + ((u >> 16) & 1);       // RNE
  return (u16)(u >> 16);
}

__device__ __forceinline__ bf16x8 ldfrag(const u16* p) {
  return *reinterpret_cast<const bf16x8*>(p);
}

__device__ __forceinline__ floatx4 mfma16(bf16x8 a, bf16x8 b, floatx4 c) {
  return __builtin_amdgcn_mfma_f32_16x16x32_bf16(a, b, c, 0, 0, 0);
}

__device__ __forceinline__ ushort4 f2b4(float4 v) {
  ushort4 r;
  r.x = f2b(v.x); r.y = f2b(v.y); r.z = f2b(v.z); r.w = f2b(v.w);
  return r;
}

// async global->LDS, 16B per lane; LDS dest = wave-uniform base + lane*16
__device__ __forceinline__ void gld16(const u16* g, u16* l) {
  __builtin_amdgcn_global_load_lds(
      (const __attribute__((address_space(1))) void*)g,
      (__attribute__((address_space(3))) void*)l, 16, 0, 0);
}

// ---------- cast fp32 -> bf16, 4 elems/thread ----------
__global__ void cast4_kernel(const float4* __restrict__ in, ushort4* __restrict__ out, int n4) {
  int i = blockIdx.x * blockDim.x + threadIdx.x;
  if (i < n4) out[i] = f2b4(in[i]);
}

// ---------- fused weight casts (W1, W2, Wq, Wk, Wv, Wo) ----------
__global__ void cast_w_kernel(const float4* __restrict__ w1, const float4* __restrict__ w2,
                              const float4* __restrict__ wq, const float4* __restrict__ wk,
                              const float4* __restrict__ wv, const float4* __restrict__ wo,
                              ushort4* __restrict__ w1b, ushort4* __restrict__ w2b,
                              ushort4* __restrict__ wqb, ushort4* __restrict__ wkb,
                              ushort4* __restrict__ wvb, ushort4* __restrict__ wob) {
  int i = blockIdx.x * blockDim.x + threadIdx.x;
  constexpr int N1 = (D4 * D) / 4;     // 262144
  constexpr int NS = (D * D) / 4;      // 65536
  if (i < N1) { w1b[i] = f2b4(w1[i]); return; }
  i -= N1;
  if (i < N1) { w2b[i] = f2b4(w2[i]); return; }
  i -= N1;
  const int sel = i >> 16, off = i & (NS - 1);
  const float4* src = sel == 0 ? wq : sel == 1 ? wk : sel == 2 ? wv : wo;
  ushort4* dst = sel == 0 ? wqb : sel == 1 ? wkb : sel == 2 ? wvb : wob;
  dst[off] = f2b4(src[off]);
}

// ---------- staged GEMM  y = A @ W.T, BK=64, optional split-K (unchanged R7) ----------
template <int EPI>
__global__ __launch_bounds__(256) void gemm_bt(
    const u16* __restrict__ A, const u16* __restrict__ W,
    const float* __restrict__ bias, void* __restrict__ out0, void* __restrict__ out1,
    int M, int N, int K, int klen) {
  __shared__ __align__(16) u16 As[2 * 128 * 32];
  __shared__ __align__(16) u16 Bs[2 * 128 * 32];
  const int wave = threadIdx.x >> 6, lane = threadIdx.x & 63;
  const int quad = lane >> 4, l16 = lane & 15;
  const int rowB = blockIdx.y * 128, colB = blockIdx.x * 128;
  const int rowW = (wave >> 1) * 64, colW = (wave & 1) * 64;
  const int koff = blockIdx.z * klen;
  void* out = blockIdx.z ? out1 : out0;

  floatx4 acc[4][4];
#pragma unroll
  for (int i = 0; i < 4; i++)
#pragma unroll
    for (int j = 0; j < 4; j++) acc[i][j] = (floatx4){0.f,0.f,0.f,0.f};

  const u16* gA = A + (size_t)(rowB + wave * 32 + (lane >> 2)) * K + koff + (lane & 3) * 8;
  const u16* gB = W + (size_t)(colB + wave * 32 + (lane >> 2)) * K + koff + (lane & 3) * 8;
  u16* lA = As + (wave * 32) * 32;
  u16* lB = Bs + (wave * 32) * 32;

  for (int kc = 0; kc < klen; kc += 64) {
#pragma unroll
    for (int kk = 0; kk < 2; kk++)
#pragma unroll
      for (int rr = 0; rr < 2; rr++) {
        gld16(gA + (size_t)rr * 16 * K + kc + kk * 32, lA + kk * 4096 + rr * 16 * 32);
        gld16(gB + (size_t)rr * 16 * K + kc + kk * 32, lB + kk * 4096 + rr * 16 * 32);
      }
    __syncthreads();

#pragma unroll
    for (int kk = 0; kk < 2; kk++) {
      bf16x8 a[4], b[4];
#pragma unroll
      for (int i = 0; i < 4; i++)
        a[i] = ldfrag(&As[kk * 4096 + (rowW + i * 16 + l16) * 32 + quad * 8]);
#pragma unroll
      for (int j = 0; j < 4; j++)
        b[j] = ldfrag(&Bs[kk * 4096 + (colW + j * 16 + l16) * 32 + quad * 8]);
#pragma unroll
      for (int i = 0; i < 4; i++)
#pragma unroll
        for (int j = 0; j < 4; j++) acc[i][j] = mfma16(a[i], b[j], acc[i][j]);
    }
    __syncthreads();
  }

#pragma unroll
  for (int i = 0; i < 4; i++) {
#pragma unroll
    for (int j = 0; j < 4; j++) {
      const int gn = colB + colW + j * 16 + l16;
      const float bv = (EPI == 1) ? bias[gn] : 0.f;
#pragma unroll
      for (int r = 0; r < 4; r++) {
        const int gm = rowB + rowW + i * 16 + quad * 4 + r;
        float v = acc[i][j][r] + bv;
        if (EPI == 0) {
          ((float*)out)[(size_t)gm * N + gn] = v;
        } else {
          v = v > 0.f ? v : 0.f;
          ((u16*)out)[(size_t)gm * N + gn] = f2b(v);
        }
      }
    }
  }
}

// ---------- staged fused QKV GEMM (unchanged R7) ----------
__global__ __launch_bounds__(256) void qkv_gemm(
    const u16* __restrict__ xb,
    const u16* __restrict__ wq, const u16* __restrict__ wk, const u16* __restrict__ wv,
    u16* __restrict__ q, u16* __restrict__ k, u16* __restrict__ vT) {
  __shared__ __align__(16) u16 As[2 * 128 * 32];
  __shared__ __align__(16) u16 Bs[2 * 128 * 32];
  const int which = blockIdx.z;
  const u16* __restrict__ W = which == 0 ? wq : (which == 1 ? wk : wv);
  const int wave = threadIdx.x >> 6, lane = threadIdx.x & 63;
  const int quad = lane >> 4, l16 = lane & 15;
  const int rowB = blockIdx.y * 128, colB = blockIdx.x * 128;
  const int rowW = (wave >> 1) * 64, colW = (wave & 1) * 64;

  floatx4 acc[4][4];
#pragma unroll
  for (int i = 0; i < 4; i++)
#pragma unroll
    for (int j = 0; j < 4; j++) acc[i][j] = (floatx4){0.f,0.f,0.f,0.f};

  const u16* gA = xb + (size_t)(rowB + wave * 32 + (lane >> 2)) * D + (lane & 3) * 8;
  const u16* gB = W + (size_t)(colB + wave * 32 + (lane >> 2)) * D + (lane & 3) * 8;
  u16* lA = As + (wave * 32) * 32;
  u16* lB = Bs + (wave * 32) * 32;

  for (int kc = 0; kc < D; kc += 64) {
#pragma unroll
    for (int kk = 0; kk < 2; kk++)
#pragma unroll
      for (int rr = 0; rr < 2; rr++) {
        gld16(gA + (size_t)rr * 16 * D + kc + kk * 32, lA + kk * 4096 + rr * 16 * 32);
        gld16(gB + (size_t)rr * 16 * D + kc + kk * 32, lB + kk * 4096 + rr * 16 * 32);
      }
    __syncthreads();

#pragma unroll
    for (int kk = 0; kk < 2; kk++) {
      bf16x8 a[4], b[4];
#pragma unroll
      for (int i = 0; i < 4; i++)
        a[i] = ldfrag(&As[kk * 4096 + (rowW + i * 16 + l16) * 32 + quad * 8]);
#pragma unroll
      for (int j = 0; j < 4; j++)
        b[j] = ldfrag(&Bs[kk * 4096 + (colW + j * 16 + l16) * 32 + quad * 8]);
#pragma unroll
      for (int i = 0; i < 4; i++)
#pragma unroll
        for (int j = 0; j < 4; j++) acc[i][j] = mfma16(a[i], b[j], acc[i][j]);
    }
    __syncthreads();
  }

  const float oscale = (which == 0) ? QSCALE : 1.0f;
  u16* dst01 = which == 0 ? q : k;
#pragma unroll
  for (int i = 0; i < 4; i++) {
#pragma unroll
    for (int j = 0; j < 4; j++) {
      const int gn = colB + colW + j * 16 + l16;   // output feature = h*64+dh
      const int h = gn >> 6, dh = gn & 63;
#pragma unroll
      for (int r = 0; r < 4; r++) {
        const int gm = rowB + rowW + i * 16 + quad * 4 + r;   // b*S + s
        const int bb = gm >> 11, s = gm & 2047;
        const u16 val = f2b(acc[i][j][r] * oscale);
        if (which < 2) {
          dst01[((((size_t)bb * H + h) * S) + s) * DH + dh] = val;
        } else {
          vT[((((size_t)bb * H + h) * DH) + dh) * S + s] = val;
        }
      }
    }
  }
}

// ---------- flash attention: block-cooperative LDS-staged K/V ----------
// 4 waves/block, wave = 64 queries, full-S key loop, tile = 64 keys.
// All 4 waves share one (b,h): K/V tiles staged ONCE per block per tile via
// global_load_lds (4 coalesced 4KB issues) -> 16x fewer VMEM instrs/CU and
// 4x less L2 traffic vs per-wave scattered gathers (the R4/R7 wall).
// Double-buffered: stage(t+1) issued before compute(t); the vmcnt drain at the
// next barrier overlaps a full compute phase.
// QK uses operand-swapped MFMA (A=K, B=Q) -> S^T in C layout: each lane holds
// 4 KEY-contiguous P values -> single ds_write_b64 per (t,i); P read back in
// A-layout via ds_read_b128 (m97-verified conflict-minimum patterns).
constexpr int PST = 72;   // P row stride in u16 (144 B, 16B-aligned)

__global__ __launch_bounds__(256, 1) void attn_kernel(
    const u16* __restrict__ q, const u16* __restrict__ k,
    const u16* __restrict__ vT, u16* __restrict__ ctxb) {
  __shared__ __align__(16) u16 kvlds[2][2][2][64 * 32]; // [buf][K/V][lo/hi] 32 KB
  __shared__ __align__(16) u16 plds[4][64 * PST];       // 36.9 KB
  __shared__ float lb[4][64];                           // 1 KB
  const int wave = threadIdx.x >> 6, lane = threadIdx.x & 63;
  const int quad = lane >> 4, l16 = lane & 15;
  // XCD swizzle for (b,h) K/V L2 locality
  const int blk = (blockIdx.x & 7) * 32 + (blockIdx.x >> 3);
  const int w = blk * 4 + wave;     // q-tile id; all 4 waves same bh (4 | 32)
  const int bh = w >> 5, qt = w & 31;
  const int bb = bh >> 3, h = bh & 7;

  // Q fragments (B-operand for QK; layout identical to A)
  const u16* qp = q + ((size_t)bh * S + qt * 64 + l16) * DH + quad * 8;
  bf16x8 qf[4][2];
#pragma unroll
  for (int t = 0; t < 4; t++) {
    qf[t][0] = ldfrag(qp + (size_t)t * 16 * DH);
    qf[t][1] = ldfrag(qp + (size_t)t * 16 * DH + 32);
  }

  // staging source addresses: thread st covers row st>>2, 16B piece st&3
  const int st = threadIdx.x;
  const int srow = st >> 2, sp = (st & 3) * 8;
  const u16* kS = k + (size_t)bh * S * DH + (size_t)srow * DH + sp;
  const u16* vS = vT + (size_t)bh * DH * S + (size_t)srow * S + sp;

  floatx4 o[4][4];
#pragma unroll
  for (int t = 0; t < 4; t++)
#pragma unroll
    for (int c = 0; c < 4; c++) o[t][c] = (floatx4){0.f,0.f,0.f,0.f};
  float lacc[4] = {0.f, 0.f, 0.f, 0.f};

  u16* myp = plds[wave];
  u16* wpb = myp + l16 * PST + quad * 4;        // + t*16*PST + i*16 (b64 writes)
  const u16* rpb = myp + l16 * PST + quad * 8;  // + t*16*PST (+32)  (b128 reads)

  // prologue stage of tile 0 into buf 0
  {
    gld16(kS, &kvlds[0][0][0][wave * 512]);
    gld16(kS + 32, &kvlds[0][0][1][wave * 512]);
    gld16(vS, &kvlds[0][1][0][wave * 512]);
    gld16(vS + 32, &kvlds[0][1][1][wave * 512]);
  }

  int buf = 0;
  for (int kt = 0; kt < S; kt += 64, buf ^= 1) {
    __syncthreads();   // stage(kt) visible; prior tile's frag reads long done

    bf16x8 kf[8], vf[8];
#pragma unroll
    for (int i = 0; i < 4; i++) {
      kf[2 * i]     = ldfrag(&kvlds[buf][0][0][(i * 16 + l16) * 32 + quad * 8]);
      kf[2 * i + 1] = ldfrag(&kvlds[buf][0][1][(i * 16 + l16) * 32 + quad * 8]);
      vf[2 * i]     = ldfrag(&kvlds[buf][1][0][(i * 16 + l16) * 32 + quad * 8]);
      vf[2 * i + 1] = ldfrag(&kvlds[buf][1][1][(i * 16 + l16) * 32 + quad * 8]);
    }

    if (kt + 64 < S) {   // issue next tile's staging; drained at next barrier
      const int nb = buf ^ 1;
      gld16(kS + (size_t)(kt + 64) * DH, &kvlds[nb][0][0][wave * 512]);
      gld16(kS + (size_t)(kt + 64) * DH + 32, &kvlds[nb][0][1][wave * 512]);
      gld16(vS + kt + 64, &kvlds[nb][1][0][wave * 512]);
      gld16(vS + kt + 96, &kvlds[nb][1][1][wave * 512]);
    }

    // QK^T (swapped: A=K, B=Q -> S^T), exp2, P write (key-contiguous b64)
#pragma unroll
    for (int t = 0; t < 4; t++) {
      floatx4 sc[4];
#pragma unroll
      for (int i = 0; i < 4; i++) {
        floatx4 z = (floatx4){0.f,0.f,0.f,0.f};
        z = mfma16(kf[2 * i], qf[t][0], z);
        z = mfma16(kf[2 * i + 1], qf[t][1], z);
        sc[i] = z;   // P^T[key = kt+i*16+quad*4+r][query = qt*64+t*16+l16]
      }
      float a = 0.f;
#pragma unroll
      for (int i = 0; i < 4; i++) {
        const float p0 = __builtin_amdgcn_exp2f(sc[i][0]);
        const float p1 = __builtin_amdgcn_exp2f(sc[i][1]);
        const float p2 = __builtin_amdgcn_exp2f(sc[i][2]);
        const float p3 = __builtin_amdgcn_exp2f(sc[i][3]);
        a += (p0 + p1) + (p2 + p3);
        ushort4 pk = {f2b(p0), f2b(p1), f2b(p2), f2b(p3)};
        *reinterpret_cast<ushort4*>(&wpb[t * 16 * PST + i * 16]) = pk;
      }
      lacc[t] += a;
    }

    // P @ V (P back in A-layout from LDS; compiler inserts lgkmcnt waits)
#pragma unroll
    for (int t = 0; t < 4; t++) {
      const bf16x8 pf0 = ldfrag(rpb + (size_t)t * 16 * PST);
      const bf16x8 pf1 = ldfrag(rpb + (size_t)t * 16 * PST + 32);
#pragma unroll
      for (int c = 0; c < 4; c++) {
        o[t][c] = mfma16(pf0, vf[2 * c], o[t][c]);
        o[t][c] = mfma16(pf1, vf[2 * c + 1], o[t][c]);
      }
    }
  }

  // l totals: each lane's lacc[t] covers keys == quad residue class; sum quads
  float lt[4];
#pragma unroll
  for (int t = 0; t < 4; t++) {
    float l = lacc[t];
    l += __shfl_xor(l, 16);
    l += __shfl_xor(l, 32);
    lt[t] = l;       // total l for query t*16 + l16 (same in all quads)
  }
  // broadcast to C-layout rows via LDS (quad 0 writes, all read)
  if (quad == 0) {
#pragma unroll
    for (int t = 0; t < 4; t++) lb[wave][t * 16 + l16] = lt[t];
  }
  __builtin_amdgcn_wave_barrier();
  float inv[4][4];
#pragma unroll
  for (int t = 0; t < 4; t++)
#pragma unroll
    for (int r = 0; r < 4; r++)
      inv[t][r] = 1.0f / lb[wave][t * 16 + quad * 4 + r];

  const size_t crow_base = ((size_t)bb * S) * D + h * DH;
#pragma unroll
  for (int t = 0; t < 4; t++)
#pragma unroll
    for (int c = 0; c < 4; c++) {
      const int dh = c * 16 + l16;
#pragma unroll
      for (int r = 0; r < 4; r++) {
        const int s = qt * 64 + t * 16 + quad * 4 + r;
        ctxb[crow_base + (size_t)s * D + dh] = f2b(o[t][c][r] * inv[t][r]);
      }
    }
}

// ---------- layernorm: out = LN(resid + ya + yb [+ pb]) ----------
template <bool BF16OUT, bool PB>
__global__ __launch_bounds__(256) void ln_kernel(
    const float* __restrict__ resid, const float* __restrict__ ya,
    const float* __restrict__ yb, const float* __restrict__ pb,
    const float* __restrict__ g, const float* __restrict__ bvec,
    float* __restrict__ outF, u16* __restrict__ outB) {
  const int wave = threadIdx.x >> 6, lane = threadIdx.x & 63;
  const int row = blockIdx.x * 4 + wave;
  const float* rp = resid + (size_t)row * D + lane * 8;
  const float* ap = ya + (size_t)row * D + lane * 8;
  const float* bp = yb + (size_t)row * D + lane * 8;
  float v[8];
  const float4 r0 = *(const float4*)rp, r1 = *(const float4*)(rp + 4);
  const float4 a0 = *(const float4*)ap, a1 = *(const float4*)(ap + 4);
  const float4 b0 = *(const float4*)bp, b1 = *(const float4*)(bp + 4);
  v[0] = r0.x + a0.x + b0.x; v[1] = r0.y + a0.y + b0.y;
  v[2] = r0.z + a0.z + b0.z; v[3] = r0.w + a0.w + b0.w;
  v[4] = r1.x + a1.x + b1.x; v[5] = r1.y + a1.y + b1.y;
  v[6] = r1.z + a1.z + b1.z; v[7] = r1.w + a1.w + b1.w;
  if (PB) {
    const float4 p0 = *(const float4*)(pb + lane * 8);
    const float4 p1 = *(const float4*)(pb + lane * 8 + 4);
    v[0] += p0.x; v[1] += p0.y; v[2] += p0.z; v[3] += p0.w;
    v[4] += p1.x; v[5] += p1.y; v[6] += p1.z; v[7] += p1.w;
  }
  float sum = 0.f;
#pragma unroll
  for (int i = 0; i < 8; i++) sum += v[i];
#pragma unroll
  for (int d = 1; d < 64; d <<= 1) sum += __shfl_xor(sum, d);
  const float mu = sum * (1.f / D);
  float vs = 0.f;
#pragma unroll
  for (int i = 0; i < 8; i++) { const float t = v[i] - mu; vs += t * t; }
#pragma unroll
  for (int d = 1; d < 64; d <<= 1) vs += __shfl_xor(vs, d);
  const float rstd = rsqrtf(vs * (1.f / D) + 1e-5f);
#pragma unroll
  for (int i = 0; i < 8; i++) {
    const int col = lane * 8 + i;
    const float o = (v[i] - mu) * rstd * g[col] + bvec[col];
    outF[(size_t)row * D + col] = o;
    if (BF16OUT) outB[(size_t)row * D + col] = f2b(o);
  }
}

// ---------- workspace layout (bytes) ----------
constexpr size_t OFF_XB  = 0;                       // 8 MB  xb [8192,512] bf16
constexpr size_t OFF_WQB = 8u << 20;                // 512 KB
constexpr size_t OFF_WKB = OFF_WQB + (512u << 10);
constexpr size_t OFF_WVB = OFF_WKB + (512u << 10);
constexpr size_t OFF_WOB = OFF_WVB + (512u << 10);
constexpr size_t OFF_W1B = 10u << 20;               // 2 MB
constexpr size_t OFF_W2B = 12u << 20;               // 2 MB
constexpr size_t OFF_Q   = 14u << 20;               // 8 MB   (reused as y1 fp32 after attn)
constexpr size_t OFF_K   = 22u << 20;               // 8 MB   (y1 second half)
constexpr size_t OFF_VT  = 30u << 20;               // 8 MB
constexpr size_t OFF_CTX = 38u << 20;               // 8 MB
constexpr size_t OFF_Y   = 46u << 20;               // 16 MB fp32 (y0, shared)
constexpr size_t OFF_H   = 62u << 20;               // 16 MB fp32
constexpr size_t OFF_HB  = 78u << 20;               // 8 MB bf16
constexpr size_t OFF_M1B = 86u << 20;               // 32 MB bf16 [8192,2048]
// total 118 MB

extern "C" void kernel_launch(void* const* d_in, const int* in_sizes, int n_in,
                              void* d_out, int out_size, void* d_ws, size_t ws_size,
                              hipStream_t stream) {
  const float* x  = (const float*)d_in[0];
  const float* Wq = (const float*)d_in[1];
  const float* Wk = (const float*)d_in[2];
  const float* Wv = (const float*)d_in[3];
  const float* Wo = (const float*)d_in[4];
  const float* W1 = (const float*)d_in[5];
  const float* b1 = (const float*)d_in[6];
  const float* W2 = (const float*)d_in[7];
  const float* b2 = (const float*)d_in[8];
  const float* g1 = (const float*)d_in[9];
  const float* bb1 = (const float*)d_in[10];
  const float* g2 = (const float*)d_in[11];
  const float* bb2 = (const float*)d_in[12];

  char* ws = (char*)d_ws;
  u16* xb  = (u16*)(ws + OFF_XB);
  u16* wqb = (u16*)(ws + OFF_WQB);
  u16* wkb = (u16*)(ws + OFF_WKB);
  u16* wvb = (u16*)(ws + OFF_WVB);
  u16* wob = (u16*)(ws + OFF_WOB);
  u16* w1b = (u16*)(ws + OFF_W1B);
  u16* w2b = (u16*)(ws + OFF_W2B);
  u16* qb  = (u16*)(ws + OFF_Q);
  u16* kb  = (u16*)(ws + OFF_K);
  u16* vtb = (u16*)(ws + OFF_VT);
  u16* ctxb = (u16*)(ws + OFF_CTX);
  float* y0 = (float*)(ws + OFF_Y);
  float* y1 = (float*)(ws + OFF_Q);     // reuses q/k region (free after attention)
  float* hf = (float*)(ws + OFF_H);
  u16* hb  = (u16*)(ws + OFF_HB);
  u16* m1b = (u16*)(ws + OFF_M1B);

  // 1. casts
  cast4_kernel<<<(M_ROWS * D / 4 + 255) / 256, 256, 0, stream>>>(
      (const float4*)x, (ushort4*)xb, M_ROWS * D / 4);
  {
    const int n4 = (D4 * D) / 4 * 2 + (D * D) / 4 * 4;   // 786432
    cast_w_kernel<<<(n4 + 255) / 256, 256, 0, stream>>>(
        (const float4*)W1, (const float4*)W2, (const float4*)Wq, (const float4*)Wk,
        (const float4*)Wv, (const float4*)Wo,
        (ushort4*)w1b, (ushort4*)w2b, (ushort4*)wqb, (ushort4*)wkb,
        (ushort4*)wvb, (ushort4*)wob);
  }

  // 2. QKV projections (staged BK=64; q pre-scaled by QSCALE); 768 blocks 3/CU
  qkv_gemm<<<dim3(D / 128, M_ROWS / 128, 3), 256, 0, stream>>>(xb, wqb, wkb, wvb, qb, kb, vtb);

  // 3. attention: 256 blocks x 4 waves x 64 queries, LDS-staged K/V
  attn_kernel<<<B * H * S / 64 / 4, 256, 0, stream>>>(qb, kb, vtb, ctxb);

  // 4. out-proj: split-K=2 -> y0,y1 partials; 512 blocks 2/CU
  gemm_bt<0><<<dim3(D / 128, M_ROWS / 128, 2), 256, 0, stream>>>(
      ctxb, wob, nullptr, y0, y1, M_ROWS, D, D, D / 2);

  // 5. h = LN(x + y0 + y1)  -> hf fp32, hb bf16
  ln_kernel<true, false><<<M_ROWS / 4, 256, 0, stream>>>(
      x, y0, y1, nullptr, g1, bb1, hf, hb);

  // 6. m1 = relu(h @ W1.T + b1) -> bf16; 1024 blocks 4/CU
  gemm_bt<1><<<dim3(D4 / 128, M_ROWS / 128, 1), 256, 0, stream>>>(
      hb, w1b, b1, m1b, nullptr, M_ROWS, D4, D, D);

  // 7. mlp partials: split-K=2 over K=2048 -> y0,y1; 512 blocks 2/CU
  gemm_bt<0><<<dim3(D / 128, M_ROWS / 128, 2), 256, 0, stream>>>(
      m1b, w2b, nullptr, y0, y1, M_ROWS, D, D4, D4 / 2);

  // 8. out = LN(h + y0 + y1 + b2)   (b2 folded in as pre-bias)
  ln_kernel<false, true><<<M_ROWS / 4, 256, 0, stream>>>(
      hf, y0, y1, b2, g2, bb2, (float*)d_out, nullptr);
}

// Round 9
// 277.553 us; speedup vs baseline: 2.0744x; 1.0304x over previous
//
#include <hip/hip_runtime.h>
#include <hip/hip_bf16.h>
#include <cstdint>
#include <cstddef>

// ---------- types ----------
typedef short bf16x8 __attribute__((ext_vector_type(8)));   // 8 bf16 (4 VGPRs) MFMA A/B frag
typedef float floatx4 __attribute__((ext_vector_type(4)));  // MFMA C/D frag
typedef unsigned short u16;

// Problem constants
constexpr int B = 4, S = 2048, D = 512, H = 8, DH = 64;
constexpr int M_ROWS = B * S;          // 8192
constexpr int D4 = 4 * D;              // 2048
// Q pre-scale: 1/sqrt(DH) * log2(e) so attention uses exp2 directly
constexpr float QSCALE = 0.18033688011112042f;

__device__ __forceinline__ u16 f2b(float f) {
  unsigned u = __builtin_bit_cast(unsigned, f);
  u += 0x7fff + ((u >> 16) & 1);       // RNE
  return (u16)(u >> 16);
}

__device__ __forceinline__ bf16x8 ldfrag(const u16* p) {
  return *reinterpret_cast<const bf16x8*>(p);
}

__device__ __forceinline__ floatx4 mfma16(bf16x8 a, bf16x8 b, floatx4 c) {
  return __builtin_amdgcn_mfma_f32_16x16x32_bf16(a, b, c, 0, 0, 0);
}

__device__ __forceinline__ ushort4 f2b4(float4 v) {
  ushort4 r;
  r.x = f2b(v.x); r.y = f2b(v.y); r.z = f2b(v.z); r.w = f2b(v.w);
  return r;
}

// async global->LDS, 16B per lane; LDS dest = wave-uniform base + lane*16
__device__ __forceinline__ void gld16(const u16* g, u16* l) {
  __builtin_amdgcn_global_load_lds(
      (const __attribute__((address_space(1))) void*)g,
      (__attribute__((address_space(3))) void*)l, 16, 0, 0);
}

// ---------- cast fp32 -> bf16, 4 elems/thread ----------
__global__ void cast4_kernel(const float4* __restrict__ in, ushort4* __restrict__ out, int n4) {
  int i = blockIdx.x * blockDim.x + threadIdx.x;
  if (i < n4) out[i] = f2b4(in[i]);
}

// ---------- fused weight casts (W1, W2, Wq, Wk, Wv, Wo) ----------
__global__ void cast_w_kernel(const float4* __restrict__ w1, const float4* __restrict__ w2,
                              const float4* __restrict__ wq, const float4* __restrict__ wk,
                              const float4* __restrict__ wv, const float4* __restrict__ wo,
                              ushort4* __restrict__ w1b, ushort4* __restrict__ w2b,
                              ushort4* __restrict__ wqb, ushort4* __restrict__ wkb,
                              ushort4* __restrict__ wvb, ushort4* __restrict__ wob) {
  int i = blockIdx.x * blockDim.x + threadIdx.x;
  constexpr int N1 = (D4 * D) / 4;     // 262144
  constexpr int NS = (D * D) / 4;      // 65536
  if (i < N1) { w1b[i] = f2b4(w1[i]); return; }
  i -= N1;
  if (i < N1) { w2b[i] = f2b4(w2[i]); return; }
  i -= N1;
  const int sel = i >> 16, off = i & (NS - 1);
  const float4* src = sel == 0 ? wq : sel == 1 ? wk : sel == 2 ? wv : wo;
  ushort4* dst = sel == 0 ? wqb : sel == 1 ? wkb : sel == 2 ? wvb : wob;
  dst[off] = f2b4(src[off]);
}

// ---------- staged GEMM  y = A @ W.T — BK=32, DOUBLE-BUFFERED single-barrier ----------
// Block tile 128x128; 4 waves 2(M)x2(N), wave tile 64x64. LDS 2x(8+8)KB = 32 KB.
// Loop: barrier (drains stage(k), issued one full iteration ago) -> issue
// stage(k+1) into the other buffer -> frag ds_read_b128 -> 16 MFMA. The vmcnt
// drain before each barrier thus overlaps a whole compute phase (R8-attn proven).
// Buffer-reuse safety: barrier's implicit lgkmcnt(0) drain means all waves'
// reads of buf^1 (iter k-1) completed before stage(k+1) overwrites it.
// blockIdx.z selects K-half [z*klen,(z+1)*klen) and out0/out1 (split-K).
// EPI 0: store fp32 (no bias); EPI 1: +bias, relu, store bf16
template <int EPI>
__global__ __launch_bounds__(256) void gemm_bt(
    const u16* __restrict__ A, const u16* __restrict__ W,
    const float* __restrict__ bias, void* __restrict__ out0, void* __restrict__ out1,
    int M, int N, int K, int klen) {
  __shared__ __align__(16) u16 As[2][128 * 32];
  __shared__ __align__(16) u16 Bs[2][128 * 32];
  const int wave = threadIdx.x >> 6, lane = threadIdx.x & 63;
  const int quad = lane >> 4, l16 = lane & 15;
  const int rowB = blockIdx.y * 128, colB = blockIdx.x * 128;
  const int rowW = (wave >> 1) * 64, colW = (wave & 1) * 64;
  const int koff = blockIdx.z * klen;
  void* out = blockIdx.z ? out1 : out0;

  floatx4 acc[4][4];
#pragma unroll
  for (int i = 0; i < 4; i++)
#pragma unroll
    for (int j = 0; j < 4; j++) acc[i][j] = (floatx4){0.f,0.f,0.f,0.f};

  // staging: wave w covers rows [w*32, w*32+32); per gld16: 16 rows x 32 cols
  const u16* gA = A + (size_t)(rowB + wave * 32 + (lane >> 2)) * K + koff + (lane & 3) * 8;
  const u16* gB = W + (size_t)(colB + wave * 32 + (lane >> 2)) * K + koff + (lane & 3) * 8;
  const int lds_off = wave * 1024;   // wave's 32 rows x 32 cols

  // prologue: stage k-chunk 0 into buf 0
#pragma unroll
  for (int rr = 0; rr < 2; rr++) {
    gld16(gA + (size_t)rr * 16 * K, &As[0][lds_off + rr * 512]);
    gld16(gB + (size_t)rr * 16 * K, &Bs[0][lds_off + rr * 512]);
  }

  int buf = 0;
  for (int kc = 0; kc < klen; kc += 32, buf ^= 1) {
    __syncthreads();   // drains vmcnt (stage kc) + lgkm (prior frag reads)

    if (kc + 32 < klen) {   // prefetch next chunk into other buffer
#pragma unroll
      for (int rr = 0; rr < 2; rr++) {
        gld16(gA + (size_t)rr * 16 * K + kc + 32, &As[buf ^ 1][lds_off + rr * 512]);
        gld16(gB + (size_t)rr * 16 * K + kc + 32, &Bs[buf ^ 1][lds_off + rr * 512]);
      }
    }

    bf16x8 a[4], b[4];
#pragma unroll
    for (int i = 0; i < 4; i++)
      a[i] = ldfrag(&As[buf][(rowW + i * 16 + l16) * 32 + quad * 8]);
#pragma unroll
    for (int j = 0; j < 4; j++)
      b[j] = ldfrag(&Bs[buf][(colW + j * 16 + l16) * 32 + quad * 8]);
#pragma unroll
    for (int i = 0; i < 4; i++)
#pragma unroll
      for (int j = 0; j < 4; j++) acc[i][j] = mfma16(a[i], b[j], acc[i][j]);
  }

#pragma unroll
  for (int i = 0; i < 4; i++) {
#pragma unroll
    for (int j = 0; j < 4; j++) {
      const int gn = colB + colW + j * 16 + l16;
      const float bv = (EPI == 1) ? bias[gn] : 0.f;
#pragma unroll
      for (int r = 0; r < 4; r++) {
        const int gm = rowB + rowW + i * 16 + quad * 4 + r;
        float v = acc[i][j][r] + bv;
        if (EPI == 0) {
          ((float*)out)[(size_t)gm * N + gn] = v;
        } else {
          v = v > 0.f ? v : 0.f;
          ((u16*)out)[(size_t)gm * N + gn] = f2b(v);
        }
      }
    }
  }
}

// ---------- staged fused QKV GEMM — same dbuf structure, scatter epilogue ----------
// z: 0->q [B,H,S,DH] (pre-scaled by QSCALE), 1->k [B,H,S,DH], 2->vT [B,H,DH,S]
__global__ __launch_bounds__(256) void qkv_gemm(
    const u16* __restrict__ xb,
    const u16* __restrict__ wq, const u16* __restrict__ wk, const u16* __restrict__ wv,
    u16* __restrict__ q, u16* __restrict__ k, u16* __restrict__ vT) {
  __shared__ __align__(16) u16 As[2][128 * 32];
  __shared__ __align__(16) u16 Bs[2][128 * 32];
  const int which = blockIdx.z;
  const u16* __restrict__ W = which == 0 ? wq : (which == 1 ? wk : wv);
  const int wave = threadIdx.x >> 6, lane = threadIdx.x & 63;
  const int quad = lane >> 4, l16 = lane & 15;
  const int rowB = blockIdx.y * 128, colB = blockIdx.x * 128;
  const int rowW = (wave >> 1) * 64, colW = (wave & 1) * 64;

  floatx4 acc[4][4];
#pragma unroll
  for (int i = 0; i < 4; i++)
#pragma unroll
    for (int j = 0; j < 4; j++) acc[i][j] = (floatx4){0.f,0.f,0.f,0.f};

  const u16* gA = xb + (size_t)(rowB + wave * 32 + (lane >> 2)) * D + (lane & 3) * 8;
  const u16* gB = W + (size_t)(colB + wave * 32 + (lane >> 2)) * D + (lane & 3) * 8;
  const int lds_off = wave * 1024;

#pragma unroll
  for (int rr = 0; rr < 2; rr++) {
    gld16(gA + (size_t)rr * 16 * D, &As[0][lds_off + rr * 512]);
    gld16(gB + (size_t)rr * 16 * D, &Bs[0][lds_off + rr * 512]);
  }

  int buf = 0;
  for (int kc = 0; kc < D; kc += 32, buf ^= 1) {
    __syncthreads();

    if (kc + 32 < D) {
#pragma unroll
      for (int rr = 0; rr < 2; rr++) {
        gld16(gA + (size_t)rr * 16 * D + kc + 32, &As[buf ^ 1][lds_off + rr * 512]);
        gld16(gB + (size_t)rr * 16 * D + kc + 32, &Bs[buf ^ 1][lds_off + rr * 512]);
      }
    }

    bf16x8 a[4], b[4];
#pragma unroll
    for (int i = 0; i < 4; i++)
      a[i] = ldfrag(&As[buf][(rowW + i * 16 + l16) * 32 + quad * 8]);
#pragma unroll
    for (int j = 0; j < 4; j++)
      b[j] = ldfrag(&Bs[buf][(colW + j * 16 + l16) * 32 + quad * 8]);
#pragma unroll
    for (int i = 0; i < 4; i++)
#pragma unroll
      for (int j = 0; j < 4; j++) acc[i][j] = mfma16(a[i], b[j], acc[i][j]);
  }

  const float oscale = (which == 0) ? QSCALE : 1.0f;
  u16* dst01 = which == 0 ? q : k;
#pragma unroll
  for (int i = 0; i < 4; i++) {
#pragma unroll
    for (int j = 0; j < 4; j++) {
      const int gn = colB + colW + j * 16 + l16;   // output feature = h*64+dh
      const int h = gn >> 6, dh = gn & 63;
#pragma unroll
      for (int r = 0; r < 4; r++) {
        const int gm = rowB + rowW + i * 16 + quad * 4 + r;   // b*S + s
        const int bb = gm >> 11, s = gm & 2047;
        const u16 val = f2b(acc[i][j][r] * oscale);
        if (which < 2) {
          dst01[((((size_t)bb * H + h) * S) + s) * DH + dh] = val;
        } else {
          vT[((((size_t)bb * H + h) * DH) + dh) * S + s] = val;
        }
      }
    }
  }
}

// ---------- flash attention: block-cooperative LDS-staged K/V (unchanged R8) ----------
constexpr int PST = 72;   // P row stride in u16 (144 B, 16B-aligned)

__global__ __launch_bounds__(256, 1) void attn_kernel(
    const u16* __restrict__ q, const u16* __restrict__ k,
    const u16* __restrict__ vT, u16* __restrict__ ctxb) {
  __shared__ __align__(16) u16 kvlds[2][2][2][64 * 32]; // [buf][K/V][lo/hi] 32 KB
  __shared__ __align__(16) u16 plds[4][64 * PST];       // 36.9 KB
  __shared__ float lb[4][64];                           // 1 KB
  const int wave = threadIdx.x >> 6, lane = threadIdx.x & 63;
  const int quad = lane >> 4, l16 = lane & 15;
  const int blk = (blockIdx.x & 7) * 32 + (blockIdx.x >> 3);
  const int w = blk * 4 + wave;     // q-tile id; all 4 waves same bh (4 | 32)
  const int bh = w >> 5, qt = w & 31;
  const int bb = bh >> 3, h = bh & 7;

  const u16* qp = q + ((size_t)bh * S + qt * 64 + l16) * DH + quad * 8;
  bf16x8 qf[4][2];
#pragma unroll
  for (int t = 0; t < 4; t++) {
    qf[t][0] = ldfrag(qp + (size_t)t * 16 * DH);
    qf[t][1] = ldfrag(qp + (size_t)t * 16 * DH + 32);
  }

  const int st = threadIdx.x;
  const int srow = st >> 2, sp = (st & 3) * 8;
  const u16* kS = k + (size_t)bh * S * DH + (size_t)srow * DH + sp;
  const u16* vS = vT + (size_t)bh * DH * S + (size_t)srow * S + sp;

  floatx4 o[4][4];
#pragma unroll
  for (int t = 0; t < 4; t++)
#pragma unroll
    for (int c = 0; c < 4; c++) o[t][c] = (floatx4){0.f,0.f,0.f,0.f};
  float lacc[4] = {0.f, 0.f, 0.f, 0.f};

  u16* myp = plds[wave];
  u16* wpb = myp + l16 * PST + quad * 4;
  const u16* rpb = myp + l16 * PST + quad * 8;

  {
    gld16(kS, &kvlds[0][0][0][wave * 512]);
    gld16(kS + 32, &kvlds[0][0][1][wave * 512]);
    gld16(vS, &kvlds[0][1][0][wave * 512]);
    gld16(vS + 32, &kvlds[0][1][1][wave * 512]);
  }

  int buf = 0;
  for (int kt = 0; kt < S; kt += 64, buf ^= 1) {
    __syncthreads();

    bf16x8 kf[8], vf[8];
#pragma unroll
    for (int i = 0; i < 4; i++) {
      kf[2 * i]     = ldfrag(&kvlds[buf][0][0][(i * 16 + l16) * 32 + quad * 8]);
      kf[2 * i + 1] = ldfrag(&kvlds[buf][0][1][(i * 16 + l16) * 32 + quad * 8]);
      vf[2 * i]     = ldfrag(&kvlds[buf][1][0][(i * 16 + l16) * 32 + quad * 8]);
      vf[2 * i + 1] = ldfrag(&kvlds[buf][1][1][(i * 16 + l16) * 32 + quad * 8]);
    }

    if (kt + 64 < S) {
      const int nb = buf ^ 1;
      gld16(kS + (size_t)(kt + 64) * DH, &kvlds[nb][0][0][wave * 512]);
      gld16(kS + (size_t)(kt + 64) * DH + 32, &kvlds[nb][0][1][wave * 512]);
      gld16(vS + kt + 64, &kvlds[nb][1][0][wave * 512]);
      gld16(vS + kt + 96, &kvlds[nb][1][1][wave * 512]);
    }

#pragma unroll
    for (int t = 0; t < 4; t++) {
      floatx4 sc[4];
#pragma unroll
      for (int i = 0; i < 4; i++) {
        floatx4 z = (floatx4){0.f,0.f,0.f,0.f};
        z = mfma16(kf[2 * i], qf[t][0], z);
        z = mfma16(kf[2 * i + 1], qf[t][1], z);
        sc[i] = z;
      }
      float a = 0.f;
#pragma unroll
      for (int i = 0; i < 4; i++) {
        const float p0 = __builtin_amdgcn_exp2f(sc[i][0]);
        const float p1 = __builtin_amdgcn_exp2f(sc[i][1]);
        const float p2 = __builtin_amdgcn_exp2f(sc[i][2]);
        const float p3 = __builtin_amdgcn_exp2f(sc[i][3]);
        a += (p0 + p1) + (p2 + p3);
        ushort4 pk = {f2b(p0), f2b(p1), f2b(p2), f2b(p3)};
        *reinterpret_cast<ushort4*>(&wpb[t * 16 * PST + i * 16]) = pk;
      }
      lacc[t] += a;
    }

#pragma unroll
    for (int t = 0; t < 4; t++) {
      const bf16x8 pf0 = ldfrag(rpb + (size_t)t * 16 * PST);
      const bf16x8 pf1 = ldfrag(rpb + (size_t)t * 16 * PST + 32);
#pragma unroll
      for (int c = 0; c < 4; c++) {
        o[t][c] = mfma16(pf0, vf[2 * c], o[t][c]);
        o[t][c] = mfma16(pf1, vf[2 * c + 1], o[t][c]);
      }
    }
  }

  float lt[4];
#pragma unroll
  for (int t = 0; t < 4; t++) {
    float l = lacc[t];
    l += __shfl_xor(l, 16);
    l += __shfl_xor(l, 32);
    lt[t] = l;
  }
  if (quad == 0) {
#pragma unroll
    for (int t = 0; t < 4; t++) lb[wave][t * 16 + l16] = lt[t];
  }
  __builtin_amdgcn_wave_barrier();
  float inv[4][4];
#pragma unroll
  for (int t = 0; t < 4; t++)
#pragma unroll
    for (int r = 0; r < 4; r++)
      inv[t][r] = 1.0f / lb[wave][t * 16 + quad * 4 + r];

  const size_t crow_base = ((size_t)bb * S) * D + h * DH;
#pragma unroll
  for (int t = 0; t < 4; t++)
#pragma unroll
    for (int c = 0; c < 4; c++) {
      const int dh = c * 16 + l16;
#pragma unroll
      for (int r = 0; r < 4; r++) {
        const int s = qt * 64 + t * 16 + quad * 4 + r;
        ctxb[crow_base + (size_t)s * D + dh] = f2b(o[t][c][r] * inv[t][r]);
      }
    }
}

// ---------- layernorm: out = LN(resid + ya + yb [+ pb]) ----------
template <bool BF16OUT, bool PB>
__global__ __launch_bounds__(256) void ln_kernel(
    const float* __restrict__ resid, const float* __restrict__ ya,
    const float* __restrict__ yb, const float* __restrict__ pb,
    const float* __restrict__ g, const float* __restrict__ bvec,
    float* __restrict__ outF, u16* __restrict__ outB) {
  const int wave = threadIdx.x >> 6, lane = threadIdx.x & 63;
  const int row = blockIdx.x * 4 + wave;
  const float* rp = resid + (size_t)row * D + lane * 8;
  const float* ap = ya + (size_t)row * D + lane * 8;
  const float* bp = yb + (size_t)row * D + lane * 8;
  float v[8];
  const float4 r0 = *(const float4*)rp, r1 = *(const float4*)(rp + 4);
  const float4 a0 = *(const float4*)ap, a1 = *(const float4*)(ap + 4);
  const float4 b0 = *(const float4*)bp, b1 = *(const float4*)(bp + 4);
  v[0] = r0.x + a0.x + b0.x; v[1] = r0.y + a0.y + b0.y;
  v[2] = r0.z + a0.z + b0.z; v[3] = r0.w + a0.w + b0.w;
  v[4] = r1.x + a1.x + b1.x; v[5] = r1.y + a1.y + b1.y;
  v[6] = r1.z + a1.z + b1.z; v[7] = r1.w + a1.w + b1.w;
  if (PB) {
    const float4 p0 = *(const float4*)(pb + lane * 8);
    const float4 p1 = *(const float4*)(pb + lane * 8 + 4);
    v[0] += p0.x; v[1] += p0.y; v[2] += p0.z; v[3] += p0.w;
    v[4] += p1.x; v[5] += p1.y; v[6] += p1.z; v[7] += p1.w;
  }
  float sum = 0.f;
#pragma unroll
  for (int i = 0; i < 8; i++) sum += v[i];
#pragma unroll
  for (int d = 1; d < 64; d <<= 1) sum += __shfl_xor(sum, d);
  const float mu = sum * (1.f / D);
  float vs = 0.f;
#pragma unroll
  for (int i = 0; i < 8; i++) { const float t = v[i] - mu; vs += t * t; }
#pragma unroll
  for (int d = 1; d < 64; d <<= 1) vs += __shfl_xor(vs, d);
  const float rstd = rsqrtf(vs * (1.f / D) + 1e-5f);
#pragma unroll
  for (int i = 0; i < 8; i++) {
    const int col = lane * 8 + i;
    const float o = (v[i] - mu) * rstd * g[col] + bvec[col];
    outF[(size_t)row * D + col] = o;
    if (BF16OUT) outB[(size_t)row * D + col] = f2b(o);
  }
}

// ---------- workspace layout (bytes) ----------
constexpr size_t OFF_XB  = 0;                       // 8 MB  xb [8192,512] bf16
constexpr size_t OFF_WQB = 8u << 20;                // 512 KB
constexpr size_t OFF_WKB = OFF_WQB + (512u << 10);
constexpr size_t OFF_WVB = OFF_WKB + (512u << 10);
constexpr size_t OFF_WOB = OFF_WVB + (512u << 10);
constexpr size_t OFF_W1B = 10u << 20;               // 2 MB
constexpr size_t OFF_W2B = 12u << 20;               // 2 MB
constexpr size_t OFF_Q   = 14u << 20;               // 8 MB   (reused as y1 fp32 after attn)
constexpr size_t OFF_K   = 22u << 20;               // 8 MB   (y1 second half)
constexpr size_t OFF_VT  = 30u << 20;               // 8 MB
constexpr size_t OFF_CTX = 38u << 20;               // 8 MB
constexpr size_t OFF_Y   = 46u << 20;               // 16 MB fp32 (y0, shared)
constexpr size_t OFF_H   = 62u << 20;               // 16 MB fp32
constexpr size_t OFF_HB  = 78u << 20;               // 8 MB bf16
constexpr size_t OFF_M1B = 86u << 20;               // 32 MB bf16 [8192,2048]
// total 118 MB

extern "C" void kernel_launch(void* const* d_in, const int* in_sizes, int n_in,
                              void* d_out, int out_size, void* d_ws, size_t ws_size,
                              hipStream_t stream) {
  const float* x  = (const float*)d_in[0];
  const float* Wq = (const float*)d_in[1];
  const float* Wk = (const float*)d_in[2];
  const float* Wv = (const float*)d_in[3];
  const float* Wo = (const float*)d_in[4];
  const float* W1 = (const float*)d_in[5];
  const float* b1 = (const float*)d_in[6];
  const float* W2 = (const float*)d_in[7];
  const float* b2 = (const float*)d_in[8];
  const float* g1 = (const float*)d_in[9];
  const float* bb1 = (const float*)d_in[10];
  const float* g2 = (const float*)d_in[11];
  const float* bb2 = (const float*)d_in[12];

  char* ws = (char*)d_ws;
  u16* xb  = (u16*)(ws + OFF_XB);
  u16* wqb = (u16*)(ws + OFF_WQB);
  u16* wkb = (u16*)(ws + OFF_WKB);
  u16* wvb = (u16*)(ws + OFF_WVB);
  u16* wob = (u16*)(ws + OFF_WOB);
  u16* w1b = (u16*)(ws + OFF_W1B);
  u16* w2b = (u16*)(ws + OFF_W2B);
  u16* qb  = (u16*)(ws + OFF_Q);
  u16* kb  = (u16*)(ws + OFF_K);
  u16* vtb = (u16*)(ws + OFF_VT);
  u16* ctxb = (u16*)(ws + OFF_CTX);
  float* y0 = (float*)(ws + OFF_Y);
  float* y1 = (float*)(ws + OFF_Q);     // reuses q/k region (free after attention)
  float* hf = (float*)(ws + OFF_H);
  u16* hb  = (u16*)(ws + OFF_HB);
  u16* m1b = (u16*)(ws + OFF_M1B);

  // 1. casts
  cast4_kernel<<<(M_ROWS * D / 4 + 255) / 256, 256, 0, stream>>>(
      (const float4*)x, (ushort4*)xb, M_ROWS * D / 4);
  {
    const int n4 = (D4 * D) / 4 * 2 + (D * D) / 4 * 4;   // 786432
    cast_w_kernel<<<(n4 + 255) / 256, 256, 0, stream>>>(
        (const float4*)W1, (const float4*)W2, (const float4*)Wq, (const float4*)Wk,
        (const float4*)Wv, (const float4*)Wo,
        (ushort4*)w1b, (ushort4*)w2b, (ushort4*)wqb, (ushort4*)wkb,
        (ushort4*)wvb, (ushort4*)wob);
  }

  // 2. QKV projections (dbuf staged; q pre-scaled by QSCALE); 768 blocks 3/CU
  qkv_gemm<<<dim3(D / 128, M_ROWS / 128, 3), 256, 0, stream>>>(xb, wqb, wkb, wvb, qb, kb, vtb);

  // 3. attention: 256 blocks x 4 waves x 64 queries, LDS-staged K/V
  attn_kernel<<<B * H * S / 64 / 4, 256, 0, stream>>>(qb, kb, vtb, ctxb);

  // 4. out-proj: split-K=2 -> y0,y1 partials; 512 blocks 2/CU
  gemm_bt<0><<<dim3(D / 128, M_ROWS / 128, 2), 256, 0, stream>>>(
      ctxb, wob, nullptr, y0, y1, M_ROWS, D, D, D / 2);

  // 5. h = LN(x + y0 + y1)  -> hf fp32, hb bf16
  ln_kernel<true, false><<<M_ROWS / 4, 256, 0, stream>>>(
      x, y0, y1, nullptr, g1, bb1, hf, hb);

  // 6. m1 = relu(h @ W1.T + b1) -> bf16; 1024 blocks 4/CU
  gemm_bt<1><<<dim3(D4 / 128, M_ROWS / 128, 1), 256, 0, stream>>>(
      hb, w1b, b1, m1b, nullptr, M_ROWS, D4, D, D);

  // 7. mlp partials: split-K=2 over K=2048 -> y0,y1; 512 blocks 2/CU
  gemm_bt<0><<<dim3(D / 128, M_ROWS / 128, 2), 256, 0, stream>>>(
      m1b, w2b, nullptr, y0, y1, M_ROWS, D, D4, D4 / 2);

  // 8. out = LN(h + y0 + y1 + b2)   (b2 folded in as pre-bias)
  ln_kernel<false, true><<<M_ROWS / 4, 256, 0, stream>>>(
      hf, y0, y1, b2, g2, bb2, (float*)d_out, nullptr);
}

// Round 10
// 261.347 us; speedup vs baseline: 2.2030x; 1.0620x over previous
//
#include <hip/hip_runtime.h>
#include <hip/hip_bf16.h>
#include <cstdint>
#include <cstddef>

// ---------- types ----------
typedef short bf16x8 __attribute__((ext_vector_type(8)));   // 8 bf16 (4 VGPRs) MFMA A/B frag
typedef float floatx4 __attribute__((ext_vector_type(4)));  // MFMA C/D frag
typedef unsigned short u16;

// Problem constants
constexpr int B = 4, S = 2048, D = 512, H = 8, DH = 64;
constexpr int M_ROWS = B * S;          // 8192
constexpr int D4 = 4 * D;              // 2048
// Q pre-scale: 1/sqrt(DH) * log2(e) so attention uses exp2 directly
constexpr float QSCALE = 0.18033688011112042f;

__device__ __forceinline__ u16 f2b(float f) {
  unsigned u = __builtin_bit_cast(unsigned, f);
  u += 0x7fff + ((u >> 16) & 1);       // RNE
  return (u16)(u >> 16);
}

__device__ __forceinline__ bf16x8 ldfrag(const u16* p) {
  return *reinterpret_cast<const bf16x8*>(p);
}

__device__ __forceinline__ floatx4 mfma16(bf16x8 a, bf16x8 b, floatx4 c) {
  return __builtin_amdgcn_mfma_f32_16x16x32_bf16(a, b, c, 0, 0, 0);
}

__device__ __forceinline__ ushort4 f2b4(float4 v) {
  ushort4 r;
  r.x = f2b(v.x); r.y = f2b(v.y); r.z = f2b(v.z); r.w = f2b(v.w);
  return r;
}

// async global->LDS, 16B per lane; LDS dest = wave-uniform base + lane*16
__device__ __forceinline__ void gld16(const u16* g, u16* l) {
  __builtin_amdgcn_global_load_lds(
      (const __attribute__((address_space(1))) void*)g,
      (__attribute__((address_space(3))) void*)l, 16, 0, 0);
}

// ---------- single fused cast launch: x, W1, W2, Wq, Wk, Wv, Wo ----------
__global__ void cast_all_kernel(const float4* __restrict__ x,
                                const float4* __restrict__ w1, const float4* __restrict__ w2,
                                const float4* __restrict__ wq, const float4* __restrict__ wk,
                                const float4* __restrict__ wv, const float4* __restrict__ wo,
                                ushort4* __restrict__ xb,
                                ushort4* __restrict__ w1b, ushort4* __restrict__ w2b,
                                ushort4* __restrict__ wqb, ushort4* __restrict__ wkb,
                                ushort4* __restrict__ wvb, ushort4* __restrict__ wob) {
  int i = blockIdx.x * blockDim.x + threadIdx.x;
  constexpr int NX = (M_ROWS * D) / 4;   // 1048576
  constexpr int N1 = (D4 * D) / 4;       // 262144
  constexpr int NS = (D * D) / 4;        // 65536
  if (i < NX) { xb[i] = f2b4(x[i]); return; }
  i -= NX;
  if (i < N1) { w1b[i] = f2b4(w1[i]); return; }
  i -= N1;
  if (i < N1) { w2b[i] = f2b4(w2[i]); return; }
  i -= N1;
  const int sel = i >> 16, off = i & (NS - 1);
  const float4* src = sel == 0 ? wq : sel == 1 ? wk : sel == 2 ? wv : wo;
  ushort4* dst = sel == 0 ? wqb : sel == 1 ? wkb : sel == 2 ? wvb : wob;
  dst[off] = f2b4(src[off]);
}

// ---------- staged GEMM  y = A @ W.T — BK=32, double-buffered (unchanged R9) ----------
template <int EPI>
__global__ __launch_bounds__(256) void gemm_bt(
    const u16* __restrict__ A, const u16* __restrict__ W,
    const float* __restrict__ bias, void* __restrict__ out0, void* __restrict__ out1,
    int M, int N, int K, int klen) {
  __shared__ __align__(16) u16 As[2][128 * 32];
  __shared__ __align__(16) u16 Bs[2][128 * 32];
  const int wave = threadIdx.x >> 6, lane = threadIdx.x & 63;
  const int quad = lane >> 4, l16 = lane & 15;
  const int rowB = blockIdx.y * 128, colB = blockIdx.x * 128;
  const int rowW = (wave >> 1) * 64, colW = (wave & 1) * 64;
  const int koff = blockIdx.z * klen;
  void* out = blockIdx.z ? out1 : out0;

  floatx4 acc[4][4];
#pragma unroll
  for (int i = 0; i < 4; i++)
#pragma unroll
    for (int j = 0; j < 4; j++) acc[i][j] = (floatx4){0.f,0.f,0.f,0.f};

  const u16* gA = A + (size_t)(rowB + wave * 32 + (lane >> 2)) * K + koff + (lane & 3) * 8;
  const u16* gB = W + (size_t)(colB + wave * 32 + (lane >> 2)) * K + koff + (lane & 3) * 8;
  const int lds_off = wave * 1024;

#pragma unroll
  for (int rr = 0; rr < 2; rr++) {
    gld16(gA + (size_t)rr * 16 * K, &As[0][lds_off + rr * 512]);
    gld16(gB + (size_t)rr * 16 * K, &Bs[0][lds_off + rr * 512]);
  }

  int buf = 0;
  for (int kc = 0; kc < klen; kc += 32, buf ^= 1) {
    __syncthreads();

    if (kc + 32 < klen) {
#pragma unroll
      for (int rr = 0; rr < 2; rr++) {
        gld16(gA + (size_t)rr * 16 * K + kc + 32, &As[buf ^ 1][lds_off + rr * 512]);
        gld16(gB + (size_t)rr * 16 * K + kc + 32, &Bs[buf ^ 1][lds_off + rr * 512]);
      }
    }

    bf16x8 a[4], b[4];
#pragma unroll
    for (int i = 0; i < 4; i++)
      a[i] = ldfrag(&As[buf][(rowW + i * 16 + l16) * 32 + quad * 8]);
#pragma unroll
    for (int j = 0; j < 4; j++)
      b[j] = ldfrag(&Bs[buf][(colW + j * 16 + l16) * 32 + quad * 8]);
#pragma unroll
    for (int i = 0; i < 4; i++)
#pragma unroll
      for (int j = 0; j < 4; j++) acc[i][j] = mfma16(a[i], b[j], acc[i][j]);
  }

#pragma unroll
  for (int i = 0; i < 4; i++) {
#pragma unroll
    for (int j = 0; j < 4; j++) {
      const int gn = colB + colW + j * 16 + l16;
      const float bv = (EPI == 1) ? bias[gn] : 0.f;
#pragma unroll
      for (int r = 0; r < 4; r++) {
        const int gm = rowB + rowW + i * 16 + quad * 4 + r;
        float v = acc[i][j][r] + bv;
        if (EPI == 0) {
          ((float*)out)[(size_t)gm * N + gn] = v;
        } else {
          v = v > 0.f ? v : 0.f;
          ((u16*)out)[(size_t)gm * N + gn] = f2b(v);
        }
      }
    }
  }
}

// ---------- staged fused QKV GEMM (unchanged R9) ----------
__global__ __launch_bounds__(256) void qkv_gemm(
    const u16* __restrict__ xb,
    const u16* __restrict__ wq, const u16* __restrict__ wk, const u16* __restrict__ wv,
    u16* __restrict__ q, u16* __restrict__ k, u16* __restrict__ vT) {
  __shared__ __align__(16) u16 As[2][128 * 32];
  __shared__ __align__(16) u16 Bs[2][128 * 32];
  const int which = blockIdx.z;
  const u16* __restrict__ W = which == 0 ? wq : (which == 1 ? wk : wv);
  const int wave = threadIdx.x >> 6, lane = threadIdx.x & 63;
  const int quad = lane >> 4, l16 = lane & 15;
  const int rowB = blockIdx.y * 128, colB = blockIdx.x * 128;
  const int rowW = (wave >> 1) * 64, colW = (wave & 1) * 64;

  floatx4 acc[4][4];
#pragma unroll
  for (int i = 0; i < 4; i++)
#pragma unroll
    for (int j = 0; j < 4; j++) acc[i][j] = (floatx4){0.f,0.f,0.f,0.f};

  const u16* gA = xb + (size_t)(rowB + wave * 32 + (lane >> 2)) * D + (lane & 3) * 8;
  const u16* gB = W + (size_t)(colB + wave * 32 + (lane >> 2)) * D + (lane & 3) * 8;
  const int lds_off = wave * 1024;

#pragma unroll
  for (int rr = 0; rr < 2; rr++) {
    gld16(gA + (size_t)rr * 16 * D, &As[0][lds_off + rr * 512]);
    gld16(gB + (size_t)rr * 16 * D, &Bs[0][lds_off + rr * 512]);
  }

  int buf = 0;
  for (int kc = 0; kc < D; kc += 32, buf ^= 1) {
    __syncthreads();

    if (kc + 32 < D) {
#pragma unroll
      for (int rr = 0; rr < 2; rr++) {
        gld16(gA + (size_t)rr * 16 * D + kc + 32, &As[buf ^ 1][lds_off + rr * 512]);
        gld16(gB + (size_t)rr * 16 * D + kc + 32, &Bs[buf ^ 1][lds_off + rr * 512]);
      }
    }

    bf16x8 a[4], b[4];
#pragma unroll
    for (int i = 0; i < 4; i++)
      a[i] = ldfrag(&As[buf][(rowW + i * 16 + l16) * 32 + quad * 8]);
#pragma unroll
    for (int j = 0; j < 4; j++)
      b[j] = ldfrag(&Bs[buf][(colW + j * 16 + l16) * 32 + quad * 8]);
#pragma unroll
    for (int i = 0; i < 4; i++)
#pragma unroll
      for (int j = 0; j < 4; j++) acc[i][j] = mfma16(a[i], b[j], acc[i][j]);
  }

  const float oscale = (which == 0) ? QSCALE : 1.0f;
  u16* dst01 = which == 0 ? q : k;
#pragma unroll
  for (int i = 0; i < 4; i++) {
#pragma unroll
    for (int j = 0; j < 4; j++) {
      const int gn = colB + colW + j * 16 + l16;   // output feature = h*64+dh
      const int h = gn >> 6, dh = gn & 63;
#pragma unroll
      for (int r = 0; r < 4; r++) {
        const int gm = rowB + rowW + i * 16 + quad * 4 + r;   // b*S + s
        const int bb = gm >> 11, s = gm & 2047;
        const u16 val = f2b(acc[i][j][r] * oscale);
        if (which < 2) {
          dst01[((((size_t)bb * H + h) * S) + s) * DH + dh] = val;
        } else {
          vT[((((size_t)bb * H + h) * DH) + dh) * S + s] = val;
        }
      }
    }
  }
}

// ---------- flash attention: 8 waves = 4 q-tiles x 2 key-halves, staged K/V ----------
// R8's block-cooperative LDS staging + R7's additive key-split combine.
// 2 waves/SIMD -> one wave's exp/pack VALU overlaps the other's MFMA/DS (m114).
// Pack-diet: bf16 via +0x8000 round-half-up + v_perm 2-at-a-time (6 ops/4 vals
// vs ~18 for scalar RNE f2b). Combine buffers overlay each pair's dead P slabs
// (2 x 9216 B >= 16384 B O + 512 B l).
constexpr int PST = 72;   // P row stride in u16 (144 B, 16B-aligned)

__global__ __launch_bounds__(512, 1) void attn_kernel(
    const u16* __restrict__ q, const u16* __restrict__ k,
    const u16* __restrict__ vT, u16* __restrict__ ctxb) {
  __shared__ __align__(16) u16 kvlds[2][2][2][2][64 * 32]; // [buf][half][K/V][lo/hi] 64 KB
  __shared__ __align__(16) u16 plds[8][64 * PST];          // 73.7 KB
  const int wave = threadIdx.x >> 6, lane = threadIdx.x & 63;
  const int quad = lane >> 4, l16 = lane & 15;
  const int pair = wave >> 1, khalf = wave & 1;
  // XCD swizzle for (b,h) K/V L2 locality
  const int blk = (blockIdx.x & 7) * 32 + (blockIdx.x >> 3);
  const int w = blk * 4 + pair;     // q-tile id; all 4 pairs same bh (4 | 32)
  const int bh = w >> 5, qt = w & 31;
  const int bb = bh >> 3, h = bh & 7;

  // Q fragments (B operand of swapped QK)
  const u16* qp = q + ((size_t)bh * S + qt * 64 + l16) * DH + quad * 8;
  bf16x8 qf[4][2];
#pragma unroll
  for (int t = 0; t < 4; t++) {
    qf[t][0] = ldfrag(qp + (size_t)t * 16 * DH);
    qf[t][1] = ldfrag(qp + (size_t)t * 16 * DH + 32);
  }

  // staging: the 4 waves of each khalf stage that half's tiles; st in [0,256)
  const int st = pair * 64 + lane;
  const int srow = st >> 2, sp = (st & 3) * 8;
  const u16* kS = k + (size_t)bh * S * DH + (size_t)(khalf * 1024 + srow) * DH + sp;
  const u16* vS = vT + (size_t)bh * DH * S + (size_t)srow * S + khalf * 1024 + sp;

  floatx4 o[4][4];
#pragma unroll
  for (int t = 0; t < 4; t++)
#pragma unroll
    for (int c = 0; c < 4; c++) o[t][c] = (floatx4){0.f,0.f,0.f,0.f};
  float lacc[4] = {0.f, 0.f, 0.f, 0.f};

  u16* myp = plds[wave];
  u16* wpb = myp + l16 * PST + quad * 4;        // +t*16*PST+i*16 (b64 writes)
  const u16* rpb = myp + l16 * PST + quad * 8;  // +t*16*PST (+32) (b128 reads)

  // prologue: stage this half's tile 0 into buf 0
  gld16(kS, &kvlds[0][khalf][0][0][pair * 512]);
  gld16(kS + 32, &kvlds[0][khalf][0][1][pair * 512]);
  gld16(vS, &kvlds[0][khalf][1][0][pair * 512]);
  gld16(vS + 32, &kvlds[0][khalf][1][1][pair * 512]);

  int buf = 0;
  for (int kt = 0; kt < S / 2; kt += 64, buf ^= 1) {
    __syncthreads();   // stage(kt) visible across the block

    bf16x8 kf[8], vf[8];
#pragma unroll
    for (int i = 0; i < 4; i++) {
      kf[2 * i]     = ldfrag(&kvlds[buf][khalf][0][0][(i * 16 + l16) * 32 + quad * 8]);
      kf[2 * i + 1] = ldfrag(&kvlds[buf][khalf][0][1][(i * 16 + l16) * 32 + quad * 8]);
      vf[2 * i]     = ldfrag(&kvlds[buf][khalf][1][0][(i * 16 + l16) * 32 + quad * 8]);
      vf[2 * i + 1] = ldfrag(&kvlds[buf][khalf][1][1][(i * 16 + l16) * 32 + quad * 8]);
    }

    if (kt + 64 < S / 2) {   // prefetch next tile; drained at next barrier
      const int nb = buf ^ 1;
      gld16(kS + (size_t)(kt + 64) * DH, &kvlds[nb][khalf][0][0][pair * 512]);
      gld16(kS + (size_t)(kt + 64) * DH + 32, &kvlds[nb][khalf][0][1][pair * 512]);
      gld16(vS + kt + 64, &kvlds[nb][khalf][1][0][pair * 512]);
      gld16(vS + kt + 96, &kvlds[nb][khalf][1][1][pair * 512]);
    }

    // QK^T (swapped: A=K, B=Q -> S^T in C layout), exp2, cheap pack -> LDS
#pragma unroll
    for (int t = 0; t < 4; t++) {
      floatx4 sc[4];
#pragma unroll
      for (int i = 0; i < 4; i++) {
        floatx4 z = (floatx4){0.f,0.f,0.f,0.f};
        z = mfma16(kf[2 * i], qf[t][0], z);
        z = mfma16(kf[2 * i + 1], qf[t][1], z);
        sc[i] = z;   // P^T[key=kt'+i*16+quad*4+r][query=qt*64+t*16+l16]
      }
      float a = 0.f;
#pragma unroll
      for (int i = 0; i < 4; i++) {
        const float p0 = __builtin_amdgcn_exp2f(sc[i][0]);
        const float p1 = __builtin_amdgcn_exp2f(sc[i][1]);
        const float p2 = __builtin_amdgcn_exp2f(sc[i][2]);
        const float p3 = __builtin_amdgcn_exp2f(sc[i][3]);
        a += (p0 + p1) + (p2 + p3);
        const unsigned lo = __builtin_amdgcn_perm(
            __builtin_bit_cast(unsigned, p1) + 0x8000u,
            __builtin_bit_cast(unsigned, p0) + 0x8000u, 0x07060302u);
        const unsigned hi = __builtin_amdgcn_perm(
            __builtin_bit_cast(unsigned, p3) + 0x8000u,
            __builtin_bit_cast(unsigned, p2) + 0x8000u, 0x07060302u);
        uint2 pk; pk.x = lo; pk.y = hi;
        *reinterpret_cast<uint2*>(&wpb[t * 16 * PST + i * 16]) = pk;
      }
      lacc[t] += a;
    }

    // P @ V (P re-read in A layout)
#pragma unroll
    for (int t = 0; t < 4; t++) {
      const bf16x8 pf0 = ldfrag(rpb + (size_t)t * 16 * PST);
      const bf16x8 pf1 = ldfrag(rpb + (size_t)t * 16 * PST + 32);
#pragma unroll
      for (int c = 0; c < 4; c++) {
        o[t][c] = mfma16(pf0, vf[2 * c], o[t][c]);
        o[t][c] = mfma16(pf1, vf[2 * c + 1], o[t][c]);
      }
    }
  }

  // per-wave l totals: lacc[t] covers this lane's quad residue; sum over quads.
  // lt[t] = l for query t*16 + l16 (uniform across quads).
  float lt[4];
#pragma unroll
  for (int t = 0; t < 4; t++) {
    float l = lacc[t];
    l += __shfl_xor(l, 16);
    l += __shfl_xor(l, 32);
    lt[t] = l;
  }

  // additive key-half combine, overlaid on the pair's dead P slabs:
  // ob 16384 B + lb0/lb1 512 B <= 18432 B
  float* ob = reinterpret_cast<float*>(plds[2 * pair]);
  float* lb0 = ob + 64 * 64;
  float* lb1 = lb0 + 64;

  __syncthreads();
  if (quad == 0) {
    float* dst = khalf ? lb1 : lb0;
#pragma unroll
    for (int t = 0; t < 4; t++) dst[t * 16 + l16] = lt[t];
  }
  if (khalf == 1) {
#pragma unroll
    for (int t = 0; t < 4; t++)
#pragma unroll
      for (int c = 0; c < 4; c++)
        *reinterpret_cast<floatx4*>(&ob[lane * 64 + (t * 4 + c) * 4]) = o[t][c];
  }
  __syncthreads();
  if (khalf == 0) {
    float inv[4][4];
#pragma unroll
    for (int t = 0; t < 4; t++)
#pragma unroll
      for (int r = 0; r < 4; r++)
        inv[t][r] = 1.0f / (lb0[t * 16 + quad * 4 + r] + lb1[t * 16 + quad * 4 + r]);

    const size_t crow_base = ((size_t)bb * S) * D + h * DH;
#pragma unroll
    for (int t = 0; t < 4; t++)
#pragma unroll
      for (int c = 0; c < 4; c++) {
        const floatx4 oo = o[t][c] +
            *reinterpret_cast<const floatx4*>(&ob[lane * 64 + (t * 4 + c) * 4]);
        const int dh = c * 16 + l16;
#pragma unroll
        for (int r = 0; r < 4; r++) {
          const int s = qt * 64 + t * 16 + quad * 4 + r;
          ctxb[crow_base + (size_t)s * D + dh] = f2b(oo[r] * inv[t][r]);
        }
      }
  }
}

// ---------- layernorm ----------
// MODE 0 (LN1): resid fp32 (x), out = bf16 hb only
// MODE 1 (LN2): resid bf16 (hb), + b2 pre-bias, out = fp32 d_out
template <int MODE>
__global__ __launch_bounds__(256) void ln_kernel(
    const void* __restrict__ resid, const float* __restrict__ ya,
    const float* __restrict__ yb, const float* __restrict__ pb,
    const float* __restrict__ g, const float* __restrict__ bvec,
    float* __restrict__ outF, u16* __restrict__ outB) {
  const int wave = threadIdx.x >> 6, lane = threadIdx.x & 63;
  const int row = blockIdx.x * 4 + wave;
  const float* ap = ya + (size_t)row * D + lane * 8;
  const float* bp = yb + (size_t)row * D + lane * 8;
  float v[8];
  const float4 a0 = *(const float4*)ap, a1 = *(const float4*)(ap + 4);
  const float4 b0 = *(const float4*)bp, b1 = *(const float4*)(bp + 4);
  v[0] = a0.x + b0.x; v[1] = a0.y + b0.y; v[2] = a0.z + b0.z; v[3] = a0.w + b0.w;
  v[4] = a1.x + b1.x; v[5] = a1.y + b1.y; v[6] = a1.z + b1.z; v[7] = a1.w + b1.w;
  if (MODE == 0) {
    const float* rp = (const float*)resid + (size_t)row * D + lane * 8;
    const float4 r0 = *(const float4*)rp, r1 = *(const float4*)(rp + 4);
    v[0] += r0.x; v[1] += r0.y; v[2] += r0.z; v[3] += r0.w;
    v[4] += r1.x; v[5] += r1.y; v[6] += r1.z; v[7] += r1.w;
  } else {
    const u16* rp = (const u16*)resid + (size_t)row * D + lane * 8;
    const ushort4 h0 = *(const ushort4*)rp, h1 = *(const ushort4*)(rp + 4);
    v[0] += __builtin_bit_cast(float, (unsigned)h0.x << 16);
    v[1] += __builtin_bit_cast(float, (unsigned)h0.y << 16);
    v[2] += __builtin_bit_cast(float, (unsigned)h0.z << 16);
    v[3] += __builtin_bit_cast(float, (unsigned)h0.w << 16);
    v[4] += __builtin_bit_cast(float, (unsigned)h1.x << 16);
    v[5] += __builtin_bit_cast(float, (unsigned)h1.y << 16);
    v[6] += __builtin_bit_cast(float, (unsigned)h1.z << 16);
    v[7] += __builtin_bit_cast(float, (unsigned)h1.w << 16);
    const float4 p0 = *(const float4*)(pb + lane * 8);
    const float4 p1 = *(const float4*)(pb + lane * 8 + 4);
    v[0] += p0.x; v[1] += p0.y; v[2] += p0.z; v[3] += p0.w;
    v[4] += p1.x; v[5] += p1.y; v[6] += p1.z; v[7] += p1.w;
  }
  float sum = 0.f;
#pragma unroll
  for (int i = 0; i < 8; i++) sum += v[i];
#pragma unroll
  for (int d = 1; d < 64; d <<= 1) sum += __shfl_xor(sum, d);
  const float mu = sum * (1.f / D);
  float vs = 0.f;
#pragma unroll
  for (int i = 0; i < 8; i++) { const float t = v[i] - mu; vs += t * t; }
#pragma unroll
  for (int d = 1; d < 64; d <<= 1) vs += __shfl_xor(vs, d);
  const float rstd = rsqrtf(vs * (1.f / D) + 1e-5f);
#pragma unroll
  for (int i = 0; i < 8; i++) {
    const int col = lane * 8 + i;
    const float o = (v[i] - mu) * rstd * g[col] + bvec[col];
    if (MODE == 0) outB[(size_t)row * D + col] = f2b(o);
    else           outF[(size_t)row * D + col] = o;
  }
}

// ---------- workspace layout (bytes) ----------
constexpr size_t OFF_XB  = 0;                       // 8 MB  xb [8192,512] bf16
constexpr size_t OFF_WQB = 8u << 20;                // 512 KB
constexpr size_t OFF_WKB = OFF_WQB + (512u << 10);
constexpr size_t OFF_WVB = OFF_WKB + (512u << 10);
constexpr size_t OFF_WOB = OFF_WVB + (512u << 10);
constexpr size_t OFF_W1B = 10u << 20;               // 2 MB
constexpr size_t OFF_W2B = 12u << 20;               // 2 MB
constexpr size_t OFF_Q   = 14u << 20;               // 8 MB  (reused as y1 fp32 after attn)
constexpr size_t OFF_K   = 22u << 20;               // 8 MB  (y1 second half)
constexpr size_t OFF_VT  = 30u << 20;               // 8 MB
constexpr size_t OFF_CTX = 38u << 20;               // 8 MB
constexpr size_t OFF_Y   = 46u << 20;               // 16 MB fp32 (y0)
constexpr size_t OFF_HB  = 78u << 20;               // 8 MB bf16 h
constexpr size_t OFF_M1B = 86u << 20;               // 32 MB bf16 [8192,2048]
// total 118 MB

extern "C" void kernel_launch(void* const* d_in, const int* in_sizes, int n_in,
                              void* d_out, int out_size, void* d_ws, size_t ws_size,
                              hipStream_t stream) {
  const float* x  = (const float*)d_in[0];
  const float* Wq = (const float*)d_in[1];
  const float* Wk = (const float*)d_in[2];
  const float* Wv = (const float*)d_in[3];
  const float* Wo = (const float*)d_in[4];
  const float* W1 = (const float*)d_in[5];
  const float* b1 = (const float*)d_in[6];
  const float* W2 = (const float*)d_in[7];
  const float* b2 = (const float*)d_in[8];
  const float* g1 = (const float*)d_in[9];
  const float* bb1 = (const float*)d_in[10];
  const float* g2 = (const float*)d_in[11];
  const float* bb2 = (const float*)d_in[12];

  char* ws = (char*)d_ws;
  u16* xb  = (u16*)(ws + OFF_XB);
  u16* wqb = (u16*)(ws + OFF_WQB);
  u16* wkb = (u16*)(ws + OFF_WKB);
  u16* wvb = (u16*)(ws + OFF_WVB);
  u16* wob = (u16*)(ws + OFF_WOB);
  u16* w1b = (u16*)(ws + OFF_W1B);
  u16* w2b = (u16*)(ws + OFF_W2B);
  u16* qb  = (u16*)(ws + OFF_Q);
  u16* kb  = (u16*)(ws + OFF_K);
  u16* vtb = (u16*)(ws + OFF_VT);
  u16* ctxb = (u16*)(ws + OFF_CTX);
  float* y0 = (float*)(ws + OFF_Y);
  float* y1 = (float*)(ws + OFF_Q);     // reuses q/k region (free after attention)
  u16* hb  = (u16*)(ws + OFF_HB);
  u16* m1b = (u16*)(ws + OFF_M1B);

  // 1. single fused cast launch (x + 6 weights)
  {
    const int n4 = (M_ROWS * D) / 4 + (D4 * D) / 4 * 2 + (D * D) / 4 * 4;  // 1835008
    cast_all_kernel<<<(n4 + 255) / 256, 256, 0, stream>>>(
        (const float4*)x, (const float4*)W1, (const float4*)W2, (const float4*)Wq,
        (const float4*)Wk, (const float4*)Wv, (const float4*)Wo,
        (ushort4*)xb, (ushort4*)w1b, (ushort4*)w2b, (ushort4*)wqb,
        (ushort4*)wkb, (ushort4*)wvb, (ushort4*)wob);
  }

  // 2. QKV projections (dbuf staged; q pre-scaled by QSCALE); 768 blocks 3/CU
  qkv_gemm<<<dim3(D / 128, M_ROWS / 128, 3), 256, 0, stream>>>(xb, wqb, wkb, wvb, qb, kb, vtb);

  // 3. attention: 256 blocks x 8 waves (4 q-tiles x 2 key-halves), staged K/V
  attn_kernel<<<B * H * S / 64 / 4, 512, 0, stream>>>(qb, kb, vtb, ctxb);

  // 4. out-proj: split-K=2 -> y0,y1 partials; 512 blocks 2/CU
  gemm_bt<0><<<dim3(D / 128, M_ROWS / 128, 2), 256, 0, stream>>>(
      ctxb, wob, nullptr, y0, y1, M_ROWS, D, D, D / 2);

  // 5. h = LN(x + y0 + y1) -> bf16 hb (fp32 h dropped; LN2 uses bf16 residual)
  ln_kernel<0><<<M_ROWS / 4, 256, 0, stream>>>(
      x, y0, y1, nullptr, g1, bb1, nullptr, hb);

  // 6. m1 = relu(h @ W1.T + b1) -> bf16; 1024 blocks 4/CU
  gemm_bt<1><<<dim3(D4 / 128, M_ROWS / 128, 1), 256, 0, stream>>>(
      hb, w1b, b1, m1b, nullptr, M_ROWS, D4, D, D);

  // 7. mlp partials: split-K=2 over K=2048 -> y0,y1; 512 blocks 2/CU
  gemm_bt<0><<<dim3(D / 128, M_ROWS / 128, 2), 256, 0, stream>>>(
      m1b, w2b, nullptr, y0, y1, M_ROWS, D, D4, D4 / 2);

  // 8. out = LN(hb + y0 + y1 + b2)   (b2 folded in as pre-bias)
  ln_kernel<1><<<M_ROWS / 4, 256, 0, stream>>>(
      hb, y0, y1, b2, g2, bb2, (float*)d_out, nullptr);
}